// Round 3
// baseline (692.814 us; speedup 1.0000x reference)
//
#include <hip/hip_runtime.h>
#include <hip/hip_bf16.h>

#define DOUT 128
#define DIN  256
#define BROWS 64            // rows per bucket
#define MAXNB 1024          // bucket-scan width cap (nb = ceil(N/64) = 782)
#define BIN_CHUNK 4096      // edges per bin_edges block
#define SCHUNK 9216         // edges per spmm LDS chunk (mean 8184 + 11 sigma)

static __device__ __forceinline__ float bf16lo_to_f(unsigned u) {
    return __uint_as_float(u << 16);
}
static __device__ __forceinline__ float bf16hi_to_f(unsigned u) {
    return __uint_as_float(u & 0xffff0000u);
}
static __device__ __forceinline__ unsigned f_to_bf16_bits(float f) {
    unsigned u = __float_as_uint(f);               // RNE round to bf16
    return (u + 0x7fffu + ((u >> 16) & 1u)) >> 16;
}

// ======================= hV = h @ V, bf16 output ===========================
// NEW layout: column-block-major. Region p (p = col>>5) holds cols 32p..32p+31
// for all rows contiguously: hV[((col>>5)*N + row)*32 + (col&31)].
// Each region = N*64B = 3.2 MB -> fits a 4 MB per-XCD L2.
__global__ __launch_bounds__(256) void hv_gemm(const float* __restrict__ h,
                                               const float* __restrict__ V,
                                               unsigned short* __restrict__ hV,
                                               int N) {
    __shared__ __align__(16) float hsT[DOUT][36];
    int r0 = blockIdx.x * 32;
    int t = threadIdx.x, col = t & 127, g = t >> 7;
    {
        int row = t >> 3, kb = t & 7;
        int sr = min(r0 + row, N - 1);
        const float4* hr = (const float4*)(h + (size_t)sr * DOUT);
        for (int i = 0; i < 4; ++i) {
            int k4 = kb + 8 * i; float4 v4 = hr[k4]; int k = 4 * k4;
            hsT[k][row] = v4.x; hsT[k+1][row] = v4.y;
            hsT[k+2][row] = v4.z; hsT[k+3][row] = v4.w;
        }
    }
    __syncthreads();
    float acc[16];
#pragma unroll
    for (int j = 0; j < 16; ++j) acc[j] = 0.f;
    int rb = g * 16;
#pragma unroll 2
    for (int k = 0; k < DOUT; ++k) {
        float v = V[k * DOUT + col];
        const float4* hp = (const float4*)&hsT[k][rb];
        float4 a0 = hp[0], a1 = hp[1], a2 = hp[2], a3 = hp[3];
        acc[0] += v*a0.x; acc[1] += v*a0.y; acc[2] += v*a0.z; acc[3] += v*a0.w;
        acc[4] += v*a1.x; acc[5] += v*a1.y; acc[6] += v*a1.z; acc[7] += v*a1.w;
        acc[8] += v*a2.x; acc[9] += v*a2.y; acc[10]+= v*a2.z; acc[11]+= v*a2.w;
        acc[12]+= v*a3.x; acc[13]+= v*a3.y; acc[14]+= v*a3.z; acc[15]+= v*a3.w;
    }
    size_t reg = ((size_t)(col >> 5) * N) * 32 + (col & 31);
#pragma unroll
    for (int j = 0; j < 16; ++j) {
        int r = r0 + rb + j;
        if (r < N) hV[reg + (size_t)r * 32] = (unsigned short)f_to_bf16_bits(acc[j]);
    }
}

// ======================= bucket histogram (validated r5) ===================
__global__ void bucket_hist(const int* __restrict__ rows, int* __restrict__ gcnt,
                            int nE, int nb) {
    __shared__ int hc[MAXNB];
    for (int i = threadIdx.x; i < nb; i += blockDim.x) hc[i] = 0;
    __syncthreads();
    for (int i = blockIdx.x * blockDim.x + threadIdx.x; i < nE;
         i += gridDim.x * blockDim.x)
        atomicAdd(&hc[rows[i] / BROWS], 1);
    __syncthreads();
    for (int i = threadIdx.x; i < nb; i += blockDim.x)
        if (hc[i]) atomicAdd(&gcnt[i], hc[i]);
}

// ============ exclusive scan of bucket counts (validated r5) ===============
__global__ __launch_bounds__(1024) void scan_buckets(const int* __restrict__ gcnt,
                                                     int* __restrict__ bptr,
                                                     int* __restrict__ gcur, int nb) {
    __shared__ int sbuf[MAXNB];
    int t = threadIdx.x;
    int c = (t < nb) ? gcnt[t] : 0;
    sbuf[t] = c;
    __syncthreads();
    for (int off = 1; off < 1024; off <<= 1) {
        int v = (t >= off) ? sbuf[t - off] : 0;
        __syncthreads();
        sbuf[t] += v;
        __syncthreads();
    }
    if (t == 0) bptr[0] = 0;
    if (t < nb) { bptr[t + 1] = sbuf[t]; gcur[t] = sbuf[t] - c; }
}

// ===== bin edges into bucket-major order, LDS counting sort (valid. r2) ====
// emits 4B record ecv4 = (col<<16)|bf16(val) + 1B local-row erow.
__global__ __launch_bounds__(1024) void bin_edges(const int* __restrict__ rows,
                                                  const int* __restrict__ cols,
                                                  const float* __restrict__ vals,
                                                  int* __restrict__ gcur,
                                                  unsigned* __restrict__ ecv4,
                                                  unsigned char* __restrict__ erow,
                                                  int nE, int nb) {
    __shared__ unsigned secv[BIN_CHUNK];                   // 16 KB
    __shared__ unsigned short srow16[BIN_CHUNK];           // 8 KB
    __shared__ int hcnt[MAXNB], sbuf[MAXNB], loff[MAXNB], lcur[MAXNB], gbase[MAXNB];
    int t = threadIdx.x;
    int base = blockIdx.x * BIN_CHUNK;
    int nvalid = min(BIN_CHUNK, nE - base);
    hcnt[t] = 0;
    __syncthreads();
    for (int j = t; j < nvalid; j += 1024)            // A: local hist
        atomicAdd(&hcnt[rows[base + j] / BROWS], 1);
    __syncthreads();
    int myc = hcnt[t];                                 // B: scan
    sbuf[t] = myc;
    __syncthreads();
    for (int off = 1; off < 1024; off <<= 1) {
        int v = (t >= off) ? sbuf[t - off] : 0;
        __syncthreads();
        sbuf[t] += v;
        __syncthreads();
    }
    int excl = sbuf[t] - myc;
    loff[t] = excl;
    lcur[t] = excl;
    if (t < nb && myc > 0) gbase[t] = atomicAdd(&gcur[t], myc);  // C: reserve
    __syncthreads();
    for (int j = t; j < nvalid; j += 1024) {          // D: place into LDS
        int i = base + j;
        unsigned r = (unsigned)rows[i];
        int bk = (int)r / BROWS;
        int slot = atomicAdd(&lcur[bk], 1);
        secv[slot] = ((unsigned)cols[i] << 16) | f_to_bf16_bits(vals[i]);
        srow16[slot] = (unsigned short)r;
    }
    __syncthreads();
    for (int j = t; j < nvalid; j += 1024) {          // E: coalesced write-out
        unsigned r = srow16[j];
        int bk = (int)r / BROWS;
        int dst = gbase[bk] + (j - loff[bk]);
        ecv4[dst] = secv[j];
        erow[dst] = (unsigned char)(r & (BROWS - 1));
    }
}

// ============== SPMM on buckets: row-sort chunk in LDS, phased gather ======
// One block (512 thr, 8 waves) per bucket of 64 rows; wave w owns rows
// w*8..w*8+7. Per chunk: counting sort by local row (segments padded to 8),
// then FOUR column phases. Phase p gathers only from hV region p (cols
// 32p..32p+31, contiguous 3.2 MB -> L2-resident per XCD). Lane layout:
// e = lane>>3 picks 1 of 8 concurrent edges, cp = lane&7 picks uint2 within
// the 64B row segment. Records broadcast from LDS; pair-unrolled (2 gathers
// in flight); shfl_xor(8/16/32) tree-reduces the 8 edge-lanes per row, then
// lanes 0..7 store/accumulate a 128B float4 run of out.
__global__ __launch_bounds__(512) void spmm_sorted(const int* __restrict__ bptr,
                                                   const unsigned* __restrict__ ecv4,
                                                   const unsigned char* __restrict__ erow,
                                                   const unsigned* __restrict__ hV,
                                                   float* __restrict__ out, int N) {
    __shared__ __align__(16) unsigned srec[SCHUNK + BROWS * 8];  // ~38 KB
    __shared__ int rcnt[BROWS], sbuf[BROWS], rptr[BROWS + 1], rcur[BROWS];
    int t = threadIdx.x;
    int b = blockIdx.x;
    int wave = t >> 6, lane = t & 63;
    int e = lane >> 3;                                 // edge sub-lane 0..7
    int cp = lane & 7;                                 // uint2 within segment
    int beg = bptr[b], end = bptr[b + 1];

    if (beg >= end) {                                  // empty bucket -> zeros
#pragma unroll
        for (int rr = 0; rr < 8; ++rr) {
            int gr = b * BROWS + wave * 8 + rr;
            if (gr < N)
                ((float2*)(out + (size_t)gr * DOUT))[lane] = make_float2(0.f, 0.f);
        }
        return;
    }

    for (int cb = beg; cb < end; cb += SCHUNK) {
        int nval = min(SCHUNK, end - cb);
        if (t < BROWS) rcnt[t] = 0;
        __syncthreads();
        for (int j = t; j < nval; j += 512)            // hist by local row
            atomicAdd(&rcnt[erow[cb + j]], 1);
        __syncthreads();
        int c = (t < BROWS) ? rcnt[t] : 0;             // scan PADDED counts
        int cp8 = (c + 7) & ~7;
        if (t < BROWS) sbuf[t] = cp8;
        __syncthreads();
        for (int off = 1; off < BROWS; off <<= 1) {
            int add = (t < BROWS && t >= off) ? sbuf[t - off] : 0;
            __syncthreads();
            if (t < BROWS) sbuf[t] += add;
            __syncthreads();
        }
        if (t == 0) rptr[0] = 0;
        if (t < BROWS) { rptr[t + 1] = sbuf[t]; rcur[t] = sbuf[t] - cp8; }
        __syncthreads();
        for (int j = t; j < nval; j += 512) {          // place sorted-by-row
            int rloc = erow[cb + j];
            int slot = atomicAdd(&rcur[rloc], 1);
            srec[slot] = ecv4[cb + j];
        }
        __syncthreads();
        if (t < BROWS) {                               // zero-fill pad slots
            int e0 = rcur[t];
            int e1 = rptr[t + 1];
            for (int k = e0; k < e1; ++k) srec[k] = 0u;
        }
        __syncthreads();

        bool first = (cb == beg);
#pragma unroll
        for (int p = 0; p < 4; ++p) {                  // column phases
            const uint2* hvp = (const uint2*)hV + (size_t)p * N * 8;
#pragma unroll
            for (int rr = 0; rr < 8; ++rr) {
                int rloc = wave * 8 + rr;
                int s = rptr[rloc];
                int ng = (rptr[rloc + 1] - s) >> 3;    // groups of 8 edges
                const unsigned* sp = &srec[s + e];
                float4 a  = make_float4(0.f, 0.f, 0.f, 0.f);
                float4 a2 = make_float4(0.f, 0.f, 0.f, 0.f);
                int ng2 = ng >> 1;
                for (int g = 0; g < ng2; ++g) {        // pair-unrolled
                    unsigned r0 = sp[g * 16];
                    unsigned r1 = sp[g * 16 + 8];
                    uint2 u0 = hvp[((r0 >> 16) << 3) | cp];
                    uint2 u1 = hvp[((r1 >> 16) << 3) | cp];
                    float v0 = bf16lo_to_f(r0);
                    float v1 = bf16lo_to_f(r1);
                    a.x  += v0 * bf16lo_to_f(u0.x); a.y  += v0 * bf16hi_to_f(u0.x);
                    a.z  += v0 * bf16lo_to_f(u0.y); a.w  += v0 * bf16hi_to_f(u0.y);
                    a2.x += v1 * bf16lo_to_f(u1.x); a2.y += v1 * bf16hi_to_f(u1.x);
                    a2.z += v1 * bf16lo_to_f(u1.y); a2.w += v1 * bf16hi_to_f(u1.y);
                }
                if (ng & 1) {                          // odd tail group
                    unsigned r0 = sp[ng2 * 16];
                    uint2 u0 = hvp[((r0 >> 16) << 3) | cp];
                    float v0 = bf16lo_to_f(r0);
                    a.x += v0 * bf16lo_to_f(u0.x); a.y += v0 * bf16hi_to_f(u0.x);
                    a.z += v0 * bf16lo_to_f(u0.y); a.w += v0 * bf16hi_to_f(u0.y);
                }
                a.x += a2.x; a.y += a2.y; a.z += a2.z; a.w += a2.w;
                a.x += __shfl_xor(a.x, 8);  a.y += __shfl_xor(a.y, 8);
                a.z += __shfl_xor(a.z, 8);  a.w += __shfl_xor(a.w, 8);
                a.x += __shfl_xor(a.x, 16); a.y += __shfl_xor(a.y, 16);
                a.z += __shfl_xor(a.z, 16); a.w += __shfl_xor(a.w, 16);
                a.x += __shfl_xor(a.x, 32); a.y += __shfl_xor(a.y, 32);
                a.z += __shfl_xor(a.z, 32); a.w += __shfl_xor(a.w, 32);
                int gr = b * BROWS + rloc;
                if (e == 0 && gr < N) {
                    float4* op = (float4*)(out + (size_t)gr * DOUT + p * 32) + cp;
                    if (!first) {
                        float4 o = *op;
                        a.x += o.x; a.y += o.y; a.z += o.z; a.w += o.w;
                    }
                    *op = a;
                }
            }
        }
        __syncthreads();
    }
}

// =============== epilogue: out = relu(x@W + out) in place (valid. r5/r6) ===
__global__ __launch_bounds__(256) void epi_xw(const float* __restrict__ x,
                                              const float* __restrict__ W,
                                              float* __restrict__ out, int N) {
    __shared__ __align__(16) float xsT[DIN][36];
    int r0 = blockIdx.x * 32;
    int t = threadIdx.x, col = t & 127, g = t >> 7;
    {
        int row = t >> 3, kb = t & 7;
        int sr = min(r0 + row, N - 1);
        const float4* xr = (const float4*)(x + (size_t)sr * DIN);
        for (int i = 0; i < 8; ++i) {
            int k4 = kb + 8 * i; float4 v4 = xr[k4]; int k = 4 * k4;
            xsT[k][row] = v4.x; xsT[k+1][row] = v4.y;
            xsT[k+2][row] = v4.z; xsT[k+3][row] = v4.w;
        }
    }
    __syncthreads();
    float acc[16];
#pragma unroll
    for (int j = 0; j < 16; ++j) acc[j] = 0.f;
    int rb = g * 16;
#pragma unroll 2
    for (int k = 0; k < DIN; ++k) {
        float w = W[k * DOUT + col];
        const float4* xp = (const float4*)&xsT[k][rb];
        float4 a0 = xp[0], a1 = xp[1], a2 = xp[2], a3 = xp[3];
        acc[0] += w*a0.x; acc[1] += w*a0.y; acc[2] += w*a0.z; acc[3] += w*a0.w;
        acc[4] += w*a1.x; acc[5] += w*a1.y; acc[6] += w*a1.z; acc[7] += w*a1.w;
        acc[8] += w*a2.x; acc[9] += w*a2.y; acc[10]+= w*a2.z; acc[11]+= w*a2.w;
        acc[12]+= w*a3.x; acc[13]+= w*a3.y; acc[14]+= w*a3.z; acc[15]+= w*a3.w;
    }
#pragma unroll
    for (int j = 0; j < 16; ++j) {
        int r = r0 + rb + j;
        if (r < N) {
            size_t o = (size_t)r * DOUT + col;
            out[o] = fmaxf(acc[j] + out[o], 0.f);
        }
    }
}

// ==================== fallback path (ws too small / N too big) =============
__global__ void spmm_atomic(const int* __restrict__ rows,
                            const int* __restrict__ cols,
                            const float* __restrict__ vals,
                            const float* __restrict__ h,
                            float* __restrict__ S, int nEdges) {
    int wave = (int)((blockIdx.x * blockDim.x + threadIdx.x) >> 6);
    int lane = threadIdx.x & 63;
    if (wave >= nEdges) return;
    int r = rows[wave], c = cols[wave];
    float v = vals[wave];
    float2 hv = ((const float2*)(h + (size_t)c * DOUT))[lane];
    float* srow = S + (size_t)r * DOUT;
    atomicAdd(srow + 2 * lane,     v * hv.x);
    atomicAdd(srow + 2 * lane + 1, v * hv.y);
}

__global__ __launch_bounds__(256) void fused_out_full(const float* __restrict__ x,
                                                      const float* __restrict__ W,
                                                      const float* __restrict__ V,
                                                      float* __restrict__ out, int N) {
    __shared__ float xs[DIN];
    __shared__ float ss[DOUT];
    int r = blockIdx.x;
    int col = threadIdx.x & 127;
    if (threadIdx.x < 128) {
        float2 xv = ((const float2*)(x + (size_t)r * DIN))[col];
        xs[2 * col] = xv.x; xs[2 * col + 1] = xv.y;
        ss[col] = out[(size_t)r * DOUT + col];
    }
    __syncthreads();
    if (threadIdx.x >= 128) return;
    float acc = 0.f;
    for (int k = 0; k < DIN; ++k) acc += xs[k] * W[k * DOUT + col];
    for (int k = 0; k < DOUT; ++k) acc += ss[k] * V[k * DOUT + col];
    out[(size_t)r * DOUT + col] = fmaxf(acc, 0.f);
}

static inline size_t align256(size_t v) { return (v + 255) & ~(size_t)255; }

extern "C" void kernel_launch(void* const* d_in, const int* in_sizes, int n_in,
                              void* d_out, int out_size, void* d_ws, size_t ws_size,
                              hipStream_t stream) {
    const float* x    = (const float*)d_in[0];
    const float* h    = (const float*)d_in[1];
    const int*   rows = (const int*)d_in[2];
    const int*   cols = (const int*)d_in[3];
    const float* vals = (const float*)d_in[4];
    const float* W    = (const float*)d_in[5];
    const float* V    = (const float*)d_in[6];
    // d_in[7] (alpha): softmax over a size-1 axis == 1 -> dead.

    int nE = in_sizes[2];              // D*E = 6.4M
    int N  = in_sizes[1] / DOUT;       // 50000
    int nb = (N + BROWS - 1) / BROWS;  // 782 buckets
    float* out = (float*)d_out;

    // ws: hV[N*128 bf16] | gcnt | bptr | gcur | ecv4[nE u32] | erow[nE u8]
    size_t o_hV   = 0;
    size_t o_gcnt = o_hV   + align256((size_t)N * DOUT * 2);
    size_t o_bptr = o_gcnt + align256((size_t)nb * 4);
    size_t o_gcur = o_bptr + align256((size_t)(nb + 1) * 4);
    size_t o_ecv4 = o_gcur + align256((size_t)nb * 4);
    size_t o_erow = o_ecv4 + align256((size_t)nE * 4);
    size_t need   = o_erow + (size_t)nE;

    if (ws_size >= need && N < 65536 && nb <= MAXNB) {
        char* p = (char*)d_ws;
        unsigned short* hV = (unsigned short*)(p + o_hV);
        int*      gcnt = (int*)(p + o_gcnt);
        int*      bptr = (int*)(p + o_bptr);
        int*      gcur = (int*)(p + o_gcur);
        unsigned* ecv4 = (unsigned*)(p + o_ecv4);
        unsigned char* erow = (unsigned char*)(p + o_erow);

        hv_gemm<<<(N + 31) / 32, 256, 0, stream>>>(h, V, hV, N);
        hipMemsetAsync(gcnt, 0, (size_t)nb * 4, stream);
        bucket_hist<<<1024, 256, 0, stream>>>(rows, gcnt, nE, nb);
        scan_buckets<<<1, 1024, 0, stream>>>(gcnt, bptr, gcur, nb);
        bin_edges<<<(nE + BIN_CHUNK - 1) / BIN_CHUNK, 1024, 0, stream>>>(
            rows, cols, vals, gcur, ecv4, erow, nE, nb);
        spmm_sorted<<<nb, 512, 0, stream>>>(bptr, ecv4, erow, (const unsigned*)hV,
                                            out, N);
        epi_xw<<<(N + 31) / 32, 256, 0, stream>>>(x, W, out, N);
    } else {
        hipMemsetAsync(out, 0, (size_t)N * DOUT * 4, stream);
        spmm_atomic<<<(nE + 3) / 4, 256, 0, stream>>>(rows, cols, vals, h, out, nE);
        fused_out_full<<<N, 128, 0, stream>>>(x, W, V, out, N);
    }
}

// Round 4
// 620.686 us; speedup vs baseline: 1.1162x; 1.1162x over previous
//
#include <hip/hip_runtime.h>
#include <hip/hip_bf16.h>

#define DOUT 128
#define DIN  256
#define BROWS 64            // rows per bucket
#define MAXNB 1024          // bucket-scan width cap (nb = ceil(N/64) = 782)
#define BIN_CHUNK 4096      // edges per bin_edges block
#define SCHUNK 9216         // edges per spmm LDS chunk (mean 8184 + 11 sigma)

static __device__ __forceinline__ float bf16lo_to_f(unsigned u) {
    return __uint_as_float(u << 16);
}
static __device__ __forceinline__ float bf16hi_to_f(unsigned u) {
    return __uint_as_float(u & 0xffff0000u);
}
static __device__ __forceinline__ unsigned f_to_bf16_bits(float f) {
    unsigned u = __float_as_uint(f);               // RNE round to bf16
    return (u + 0x7fffu + ((u >> 16) & 1u)) >> 16;
}

// ======================= hV = h @ V, bf16 output ===========================
// Region layout (validated r3: fetch 560->240 MB): region p = col>>5 holds
// cols 32p..32p+31 for all rows contiguously; row stride 32 bf16 = 16 u32.
// NEW (r4): 2 cols/thread (float2 V loads, u32 packed store) -> half the
// ds_read_b128 per FMA and half the V L2 traffic vs r3.
__global__ __launch_bounds__(256) void hv_gemm(const float* __restrict__ h,
                                               const float* __restrict__ V,
                                               unsigned* __restrict__ hVu,
                                               int N) {
    __shared__ __align__(16) float hsT[DOUT][36];
    int r0 = blockIdx.x * 32;
    int t = threadIdx.x;
    int c = t & 63;              // col pair: cols {2c, 2c+1}
    int g = t >> 6;              // row group 0..3 (rows g*8..g*8+7)
    {
        int row = t >> 3, kb = t & 7;
        int sr = min(r0 + row, N - 1);
        const float4* hr = (const float4*)(h + (size_t)sr * DOUT);
        for (int i = 0; i < 4; ++i) {
            int k4 = kb + 8 * i; float4 v4 = hr[k4]; int k = 4 * k4;
            hsT[k][row] = v4.x; hsT[k+1][row] = v4.y;
            hsT[k+2][row] = v4.z; hsT[k+3][row] = v4.w;
        }
    }
    __syncthreads();
    float2 acc[8];
#pragma unroll
    for (int j = 0; j < 8; ++j) acc[j] = make_float2(0.f, 0.f);
    int rb = g * 8;
#pragma unroll 2
    for (int k = 0; k < DOUT; ++k) {
        float2 v2 = ((const float2*)(V + k * DOUT))[c];
        const float4* hp = (const float4*)&hsT[k][rb];
        float4 a0 = hp[0], a1 = hp[1];
        acc[0].x += v2.x*a0.x; acc[0].y += v2.y*a0.x;
        acc[1].x += v2.x*a0.y; acc[1].y += v2.y*a0.y;
        acc[2].x += v2.x*a0.z; acc[2].y += v2.y*a0.z;
        acc[3].x += v2.x*a0.w; acc[3].y += v2.y*a0.w;
        acc[4].x += v2.x*a1.x; acc[4].y += v2.y*a1.x;
        acc[5].x += v2.x*a1.y; acc[5].y += v2.y*a1.y;
        acc[6].x += v2.x*a1.z; acc[6].y += v2.y*a1.z;
        acc[7].x += v2.x*a1.w; acc[7].y += v2.y*a1.w;
    }
    // region p = c>>4; u32 index within row = c&15 (u32 lo = even col)
    size_t regbase = (size_t)(c >> 4) * N * 16 + (unsigned)(c & 15);
#pragma unroll
    for (int j = 0; j < 8; ++j) {
        int r = r0 + rb + j;
        if (r < N)
            hVu[regbase + (size_t)r * 16] =
                f_to_bf16_bits(acc[j].x) | (f_to_bf16_bits(acc[j].y) << 16);
    }
}

// ======================= bucket histogram (validated r5) ===================
__global__ void bucket_hist(const int* __restrict__ rows, int* __restrict__ gcnt,
                            int nE, int nb) {
    __shared__ int hc[MAXNB];
    for (int i = threadIdx.x; i < nb; i += blockDim.x) hc[i] = 0;
    __syncthreads();
    for (int i = blockIdx.x * blockDim.x + threadIdx.x; i < nE;
         i += gridDim.x * blockDim.x)
        atomicAdd(&hc[rows[i] / BROWS], 1);
    __syncthreads();
    for (int i = threadIdx.x; i < nb; i += blockDim.x)
        if (hc[i]) atomicAdd(&gcnt[i], hc[i]);
}

// ============ exclusive scan of bucket counts (validated r5) ===============
__global__ __launch_bounds__(1024) void scan_buckets(const int* __restrict__ gcnt,
                                                     int* __restrict__ bptr,
                                                     int* __restrict__ gcur, int nb) {
    __shared__ int sbuf[MAXNB];
    int t = threadIdx.x;
    int c = (t < nb) ? gcnt[t] : 0;
    sbuf[t] = c;
    __syncthreads();
    for (int off = 1; off < 1024; off <<= 1) {
        int v = (t >= off) ? sbuf[t - off] : 0;
        __syncthreads();
        sbuf[t] += v;
        __syncthreads();
    }
    if (t == 0) bptr[0] = 0;
    if (t < nb) { bptr[t + 1] = sbuf[t]; gcur[t] = sbuf[t] - c; }
}

// ===== bin edges into bucket-major order, LDS counting sort (valid. r2) ====
// emits 4B record ecv4 = (col<<16)|bf16(val) + 1B local-row erow.
__global__ __launch_bounds__(1024) void bin_edges(const int* __restrict__ rows,
                                                  const int* __restrict__ cols,
                                                  const float* __restrict__ vals,
                                                  int* __restrict__ gcur,
                                                  unsigned* __restrict__ ecv4,
                                                  unsigned char* __restrict__ erow,
                                                  int nE, int nb) {
    __shared__ unsigned secv[BIN_CHUNK];                   // 16 KB
    __shared__ unsigned short srow16[BIN_CHUNK];           // 8 KB
    __shared__ int hcnt[MAXNB], sbuf[MAXNB], loff[MAXNB], lcur[MAXNB], gbase[MAXNB];
    int t = threadIdx.x;
    int base = blockIdx.x * BIN_CHUNK;
    int nvalid = min(BIN_CHUNK, nE - base);
    hcnt[t] = 0;
    __syncthreads();
    for (int j = t; j < nvalid; j += 1024)            // A: local hist
        atomicAdd(&hcnt[rows[base + j] / BROWS], 1);
    __syncthreads();
    int myc = hcnt[t];                                 // B: scan
    sbuf[t] = myc;
    __syncthreads();
    for (int off = 1; off < 1024; off <<= 1) {
        int v = (t >= off) ? sbuf[t - off] : 0;
        __syncthreads();
        sbuf[t] += v;
        __syncthreads();
    }
    int excl = sbuf[t] - myc;
    loff[t] = excl;
    lcur[t] = excl;
    if (t < nb && myc > 0) gbase[t] = atomicAdd(&gcur[t], myc);  // C: reserve
    __syncthreads();
    for (int j = t; j < nvalid; j += 1024) {          // D: place into LDS
        int i = base + j;
        unsigned r = (unsigned)rows[i];
        int bk = (int)r / BROWS;
        int slot = atomicAdd(&lcur[bk], 1);
        secv[slot] = ((unsigned)cols[i] << 16) | f_to_bf16_bits(vals[i]);
        srow16[slot] = (unsigned short)r;
    }
    __syncthreads();
    for (int j = t; j < nvalid; j += 1024) {          // E: coalesced write-out
        unsigned r = srow16[j];
        int bk = (int)r / BROWS;
        int dst = gbase[bk] + (j - loff[bk]);
        ecv4[dst] = secv[j];
        erow[dst] = (unsigned char)(r & (BROWS - 1));
    }
}

// ============== SPMM: row-sorted LDS chunk, 4 L2-phases, private acc =======
// One block (512 thr, 8 waves) per bucket of 64 rows; wave w owns rows
// w*8..w*8+7. Per chunk: counting sort by local row (segments padded to 8),
// then 4 column phases (phase p gathers only from the 3.2 MB hV region p ->
// per-XCD L2-resident; mechanism validated r3: fetch 560->240 MB).
// r4 fix of r3's regression: fixed lane->(row, 4-col) mapping. rg=lane>>3
// picks the wave's row, cp=lane&7 picks a uint2 (4 cols) in the region.
// Each lane walks its row's segment (uint4 LDS reads = 4 edges, 4 dwordx2
// gathers in flight), accumulating into PRIVATE float4 acc[4] that persists
// across chunks AND phases: zero shuffles, zero out-RMW, one store at end.
__global__ __launch_bounds__(512) void spmm_sorted(const int* __restrict__ bptr,
                                                   const unsigned* __restrict__ ecv4,
                                                   const unsigned char* __restrict__ erow,
                                                   const unsigned* __restrict__ hV,
                                                   float* __restrict__ out, int N) {
    __shared__ __align__(16) unsigned srec[SCHUNK + BROWS * 8];  // ~38 KB
    __shared__ int rcnt[BROWS], sbuf[BROWS], rptr[BROWS + 1], rcur[BROWS];
    int t = threadIdx.x;
    int b = blockIdx.x;
    int wave = t >> 6, lane = t & 63;
    int rg = lane >> 3;                                // row within wave 0..7
    int cp = lane & 7;                                 // uint2 within region row
    int rloc = wave * 8 + rg;
    int beg = bptr[b], end = bptr[b + 1];

    float4 acc[4];
#pragma unroll
    for (int p = 0; p < 4; ++p) acc[p] = make_float4(0.f, 0.f, 0.f, 0.f);

    for (int cb = beg; cb < end; cb += SCHUNK) {
        int nval = min(SCHUNK, end - cb);
        if (t < BROWS) rcnt[t] = 0;
        __syncthreads();
        for (int j = t; j < nval; j += 512)            // hist by local row
            atomicAdd(&rcnt[erow[cb + j]], 1);
        __syncthreads();
        int c = (t < BROWS) ? rcnt[t] : 0;             // scan PADDED counts
        int cp8 = (c + 7) & ~7;
        if (t < BROWS) sbuf[t] = cp8;
        __syncthreads();
        for (int off = 1; off < BROWS; off <<= 1) {
            int add = (t < BROWS && t >= off) ? sbuf[t - off] : 0;
            __syncthreads();
            if (t < BROWS) sbuf[t] += add;
            __syncthreads();
        }
        if (t == 0) rptr[0] = 0;
        if (t < BROWS) { rptr[t + 1] = sbuf[t]; rcur[t] = sbuf[t] - cp8; }
        __syncthreads();
        for (int j = t; j < nval; j += 512) {          // place sorted-by-row
            int rl = erow[cb + j];
            int slot = atomicAdd(&rcur[rl], 1);
            srec[slot] = ecv4[cb + j];
        }
        __syncthreads();
        if (t < BROWS) {                               // zero-fill pad slots
            int e0 = rcur[t];                          // pad rec = col0,val+0
            int e1 = rptr[t + 1];
            for (int k = e0; k < e1; ++k) srec[k] = 0u;
        }
        __syncthreads();

        int s = rptr[rloc], e = rptr[rloc + 1];        // this lane's segment
#pragma unroll
        for (int p = 0; p < 4; ++p) {                  // L2-resident phases
            const uint2* hvp = (const uint2*)hV + (size_t)p * N * 8;
            float4 a = acc[p];
            for (int k = s; k < e; k += 4) {           // 4 edges, 4 gathers
                uint4 q = *(const uint4*)&srec[k];     // 16B aligned (s%8==0)
                uint2 u0 = hvp[((q.x >> 16) << 3) | cp];
                uint2 u1 = hvp[((q.y >> 16) << 3) | cp];
                uint2 u2 = hvp[((q.z >> 16) << 3) | cp];
                uint2 u3 = hvp[((q.w >> 16) << 3) | cp];
                float v0 = bf16lo_to_f(q.x);
                float v1 = bf16lo_to_f(q.y);
                float v2 = bf16lo_to_f(q.z);
                float v3 = bf16lo_to_f(q.w);
                a.x += v0 * bf16lo_to_f(u0.x); a.y += v0 * bf16hi_to_f(u0.x);
                a.z += v0 * bf16lo_to_f(u0.y); a.w += v0 * bf16hi_to_f(u0.y);
                a.x += v1 * bf16lo_to_f(u1.x); a.y += v1 * bf16hi_to_f(u1.x);
                a.z += v1 * bf16lo_to_f(u1.y); a.w += v1 * bf16hi_to_f(u1.y);
                a.x += v2 * bf16lo_to_f(u2.x); a.y += v2 * bf16hi_to_f(u2.x);
                a.z += v2 * bf16lo_to_f(u2.y); a.w += v2 * bf16hi_to_f(u2.y);
                a.x += v3 * bf16lo_to_f(u3.x); a.y += v3 * bf16hi_to_f(u3.x);
                a.z += v3 * bf16lo_to_f(u3.y); a.w += v3 * bf16hi_to_f(u3.y);
            }
            acc[p] = a;
        }
        __syncthreads();
    }
    int row = b * BROWS + rloc;                        // single coalesced store
    if (row < N) {
#pragma unroll
        for (int p = 0; p < 4; ++p)
            ((float4*)(out + (size_t)row * DOUT + p * 32))[cp] = acc[p];
    }
}

// =============== epilogue: out = relu(x@W + out) in place ==================
// r4: 2 cols/thread (float2 W loads) -> half LDS b128 per FMA, half W L2.
__global__ __launch_bounds__(256) void epi_xw(const float* __restrict__ x,
                                              const float* __restrict__ W,
                                              float* __restrict__ out, int N) {
    __shared__ __align__(16) float xsT[DIN][36];
    int r0 = blockIdx.x * 32;
    int t = threadIdx.x;
    int c = t & 63;              // col pair: cols {2c, 2c+1}
    int g = t >> 6;              // row group 0..3 (rows g*8..g*8+7)
    {
        int row = t >> 3, kb = t & 7;
        int sr = min(r0 + row, N - 1);
        const float4* xr = (const float4*)(x + (size_t)sr * DIN);
        for (int i = 0; i < 8; ++i) {
            int k4 = kb + 8 * i; float4 v4 = xr[k4]; int k = 4 * k4;
            xsT[k][row] = v4.x; xsT[k+1][row] = v4.y;
            xsT[k+2][row] = v4.z; xsT[k+3][row] = v4.w;
        }
    }
    __syncthreads();
    float2 acc[8];
#pragma unroll
    for (int j = 0; j < 8; ++j) acc[j] = make_float2(0.f, 0.f);
    int rb = g * 8;
#pragma unroll 2
    for (int k = 0; k < DIN; ++k) {
        float2 w2 = ((const float2*)(W + k * DOUT))[c];
        const float4* xp = (const float4*)&xsT[k][rb];
        float4 a0 = xp[0], a1 = xp[1];
        acc[0].x += w2.x*a0.x; acc[0].y += w2.y*a0.x;
        acc[1].x += w2.x*a0.y; acc[1].y += w2.y*a0.y;
        acc[2].x += w2.x*a0.z; acc[2].y += w2.y*a0.z;
        acc[3].x += w2.x*a0.w; acc[3].y += w2.y*a0.w;
        acc[4].x += w2.x*a1.x; acc[4].y += w2.y*a1.x;
        acc[5].x += w2.x*a1.y; acc[5].y += w2.y*a1.y;
        acc[6].x += w2.x*a1.z; acc[6].y += w2.y*a1.z;
        acc[7].x += w2.x*a1.w; acc[7].y += w2.y*a1.w;
    }
#pragma unroll
    for (int j = 0; j < 8; ++j) {
        int r = r0 + rb + j;
        if (r < N) {
            float2* op = (float2*)(out + (size_t)r * DOUT) + c;
            float2 o = *op;
            o.x = fmaxf(acc[j].x + o.x, 0.f);
            o.y = fmaxf(acc[j].y + o.y, 0.f);
            *op = o;
        }
    }
}

// ==================== fallback path (ws too small / N too big) =============
__global__ void spmm_atomic(const int* __restrict__ rows,
                            const int* __restrict__ cols,
                            const float* __restrict__ vals,
                            const float* __restrict__ h,
                            float* __restrict__ S, int nEdges) {
    int wave = (int)((blockIdx.x * blockDim.x + threadIdx.x) >> 6);
    int lane = threadIdx.x & 63;
    if (wave >= nEdges) return;
    int r = rows[wave], c = cols[wave];
    float v = vals[wave];
    float2 hv = ((const float2*)(h + (size_t)c * DOUT))[lane];
    float* srow = S + (size_t)r * DOUT;
    atomicAdd(srow + 2 * lane,     v * hv.x);
    atomicAdd(srow + 2 * lane + 1, v * hv.y);
}

__global__ __launch_bounds__(256) void fused_out_full(const float* __restrict__ x,
                                                      const float* __restrict__ W,
                                                      const float* __restrict__ V,
                                                      float* __restrict__ out, int N) {
    __shared__ float xs[DIN];
    __shared__ float ss[DOUT];
    int r = blockIdx.x;
    int col = threadIdx.x & 127;
    if (threadIdx.x < 128) {
        float2 xv = ((const float2*)(x + (size_t)r * DIN))[col];
        xs[2 * col] = xv.x; xs[2 * col + 1] = xv.y;
        ss[col] = out[(size_t)r * DOUT + col];
    }
    __syncthreads();
    if (threadIdx.x >= 128) return;
    float acc = 0.f;
    for (int k = 0; k < DIN; ++k) acc += xs[k] * W[k * DOUT + col];
    for (int k = 0; k < DOUT; ++k) acc += ss[k] * V[k * DOUT + col];
    out[(size_t)r * DOUT + col] = fmaxf(acc, 0.f);
}

static inline size_t align256(size_t v) { return (v + 255) & ~(size_t)255; }

extern "C" void kernel_launch(void* const* d_in, const int* in_sizes, int n_in,
                              void* d_out, int out_size, void* d_ws, size_t ws_size,
                              hipStream_t stream) {
    const float* x    = (const float*)d_in[0];
    const float* h    = (const float*)d_in[1];
    const int*   rows = (const int*)d_in[2];
    const int*   cols = (const int*)d_in[3];
    const float* vals = (const float*)d_in[4];
    const float* W    = (const float*)d_in[5];
    const float* V    = (const float*)d_in[6];
    // d_in[7] (alpha): softmax over a size-1 axis == 1 -> dead.

    int nE = in_sizes[2];              // D*E = 6.4M
    int N  = in_sizes[1] / DOUT;       // 50000
    int nb = (N + BROWS - 1) / BROWS;  // 782 buckets
    float* out = (float*)d_out;

    // ws: hV[N*128 bf16] | gcnt | bptr | gcur | ecv4[nE u32] | erow[nE u8]
    size_t o_hV   = 0;
    size_t o_gcnt = o_hV   + align256((size_t)N * DOUT * 2);
    size_t o_bptr = o_gcnt + align256((size_t)nb * 4);
    size_t o_gcur = o_bptr + align256((size_t)(nb + 1) * 4);
    size_t o_ecv4 = o_gcur + align256((size_t)nb * 4);
    size_t o_erow = o_ecv4 + align256((size_t)nE * 4);
    size_t need   = o_erow + (size_t)nE;

    if (ws_size >= need && N < 65536 && nb <= MAXNB) {
        char* p = (char*)d_ws;
        unsigned* hVu = (unsigned*)(p + o_hV);
        int*      gcnt = (int*)(p + o_gcnt);
        int*      bptr = (int*)(p + o_bptr);
        int*      gcur = (int*)(p + o_gcur);
        unsigned* ecv4 = (unsigned*)(p + o_ecv4);
        unsigned char* erow = (unsigned char*)(p + o_erow);

        hv_gemm<<<(N + 31) / 32, 256, 0, stream>>>(h, V, hVu, N);
        hipMemsetAsync(gcnt, 0, (size_t)nb * 4, stream);
        bucket_hist<<<1024, 256, 0, stream>>>(rows, gcnt, nE, nb);
        scan_buckets<<<1, 1024, 0, stream>>>(gcnt, bptr, gcur, nb);
        bin_edges<<<(nE + BIN_CHUNK - 1) / BIN_CHUNK, 1024, 0, stream>>>(
            rows, cols, vals, gcur, ecv4, erow, nE, nb);
        spmm_sorted<<<nb, 512, 0, stream>>>(bptr, ecv4, erow, hVu, out, N);
        epi_xw<<<(N + 31) / 32, 256, 0, stream>>>(x, W, out, N);
    } else {
        hipMemsetAsync(out, 0, (size_t)N * DOUT * 4, stream);
        spmm_atomic<<<(nE + 3) / 4, 256, 0, stream>>>(rows, cols, vals, h, out, nE);
        fused_out_full<<<N, 128, 0, stream>>>(x, W, V, out, N);
    }
}

// Round 5
// 499.247 us; speedup vs baseline: 1.3877x; 1.2432x over previous
//
#include <hip/hip_runtime.h>
#include <hip/hip_bf16.h>

#define DOUT 128
#define DIN  256
#define BROWS 64            // rows per bucket
#define MAXNB 1024          // bucket-scan width cap (nb = ceil(N/64) = 782)
#define BIN_CHUNK 4096      // edges per bin_edges block
#define SCHUNK 9216         // edges per spmm LDS chunk (mean 8184 + 11 sigma)

typedef __attribute__((ext_vector_type(8))) short bf16x8;
typedef __attribute__((ext_vector_type(4))) float f32x4;
union FragU { uint4 q; bf16x8 f; };

static __device__ __forceinline__ float bf16lo_to_f(unsigned u) {
    return __uint_as_float(u << 16);
}
static __device__ __forceinline__ float bf16hi_to_f(unsigned u) {
    return __uint_as_float(u & 0xffff0000u);
}
static __device__ __forceinline__ unsigned f_to_bf16_bits(float f) {
    unsigned u = __float_as_uint(f);               // RNE round to bf16
    return (u + 0x7fffu + ((u >> 16) & 1u)) >> 16;
}
static __device__ __forceinline__ unsigned pack2(float a, float b) {
    return f_to_bf16_bits(a) | (f_to_bf16_bits(b) << 16);
}

// ========== tiny: W^T, V^T -> bf16 (done once, 96 KB total) ================
__global__ __launch_bounds__(256) void conv_wv(const float* __restrict__ W,
                                               const float* __restrict__ V,
                                               unsigned short* __restrict__ WT,
                                               unsigned short* __restrict__ VT) {
    int n = blockIdx.x;                 // 0..127 output row (= col of W/V)
    int t = threadIdx.x;                // 0..255
    WT[n * 256 + t] = (unsigned short)f_to_bf16_bits(W[t * DOUT + n]);
    if (t < 128) VT[n * 128 + t] = (unsigned short)f_to_bf16_bits(V[t * DOUT + n]);
}

// ======================= hV = h @ V via MFMA, bf16 row-major out ===========
// Block: 64 rows x 128 cols, 4 waves (2x2 of 32x64). K=128 in 4 steps of 32.
// A (h) staged in LDS as packed bf16 (row stride 20 u32: 2-way max conflict);
// B = VT bf16 read straight from global (32 KB, L2-resident chip-wide).
// Frag layout (16x16x32): A/B lane l -> m|n = l&15, k = 8*(l>>4)+j;
// C/D lane l, reg -> col = l&15, row = 4*(l>>4)+reg [guide §3, m89].
__global__ __launch_bounds__(256) void hv_gemm(const float* __restrict__ h,
                                               const unsigned* __restrict__ VTu,
                                               unsigned short* __restrict__ hV,
                                               int N) {
    __shared__ unsigned xs[64 * 20];
    int t = threadIdx.x;
    int r0 = blockIdx.x * 64;
    int w = t >> 6, l = t & 63;
    int wm = w >> 1, wn = w & 1;
    int lm = l & 15, lk = l >> 4;
    f32x4 acc[2][4];
#pragma unroll
    for (int i = 0; i < 2; ++i)
#pragma unroll
        for (int j = 0; j < 4; ++j) acc[i][j] = (f32x4){0.f, 0.f, 0.f, 0.f};

    int srow = min(r0 + (t >> 2), N - 1);
    const float* hrow = h + (size_t)srow * DOUT + (t & 3) * 8;
    unsigned* xsw = &xs[(t >> 2) * 20 + (t & 3) * 4];

    for (int k0 = 0; k0 < DOUT; k0 += 32) {
        float4 f0 = *(const float4*)(hrow + k0);
        float4 f1 = *(const float4*)(hrow + k0 + 4);
        ((uint4*)xsw)[0] = make_uint4(pack2(f0.x, f0.y), pack2(f0.z, f0.w),
                                      pack2(f1.x, f1.y), pack2(f1.z, f1.w));
        __syncthreads();
        FragU a[2], b[4];
#pragma unroll
        for (int i = 0; i < 2; ++i)
            a[i].q = *(const uint4*)&xs[(wm * 32 + i * 16 + lm) * 20 + lk * 4];
#pragma unroll
        for (int j = 0; j < 4; ++j)
            b[j].q = *(const uint4*)(VTu + (size_t)(wn * 64 + j * 16 + lm) * 64 +
                                     (k0 >> 1) + lk * 4);
#pragma unroll
        for (int i = 0; i < 2; ++i)
#pragma unroll
            for (int j = 0; j < 4; ++j)
                acc[i][j] = __builtin_amdgcn_mfma_f32_16x16x32_bf16(
                    a[i].f, b[j].f, acc[i][j], 0, 0, 0);
        __syncthreads();
    }
#pragma unroll
    for (int i = 0; i < 2; ++i)
#pragma unroll
        for (int j = 0; j < 4; ++j) {
            int gr0 = r0 + wm * 32 + i * 16 + lk * 4;
            int gc = wn * 64 + j * 16 + lm;
#pragma unroll
            for (int r = 0; r < 4; ++r) {
                int gr = gr0 + r;
                if (gr < N)
                    hV[(size_t)gr * DOUT + gc] =
                        (unsigned short)f_to_bf16_bits(acc[i][j][r]);
            }
        }
}

// ======================= bucket histogram (validated r5) ===================
__global__ void bucket_hist(const int* __restrict__ rows, int* __restrict__ gcnt,
                            int nE, int nb) {
    __shared__ int hc[MAXNB];
    for (int i = threadIdx.x; i < nb; i += blockDim.x) hc[i] = 0;
    __syncthreads();
    for (int i = blockIdx.x * blockDim.x + threadIdx.x; i < nE;
         i += gridDim.x * blockDim.x)
        atomicAdd(&hc[rows[i] / BROWS], 1);
    __syncthreads();
    for (int i = threadIdx.x; i < nb; i += blockDim.x)
        if (hc[i]) atomicAdd(&gcnt[i], hc[i]);
}

// ============ exclusive scan of bucket counts (validated r5) ===============
__global__ __launch_bounds__(1024) void scan_buckets(const int* __restrict__ gcnt,
                                                     int* __restrict__ bptr,
                                                     int* __restrict__ gcur, int nb) {
    __shared__ int sbuf[MAXNB];
    int t = threadIdx.x;
    int c = (t < nb) ? gcnt[t] : 0;
    sbuf[t] = c;
    __syncthreads();
    for (int off = 1; off < 1024; off <<= 1) {
        int v = (t >= off) ? sbuf[t - off] : 0;
        __syncthreads();
        sbuf[t] += v;
        __syncthreads();
    }
    if (t == 0) bptr[0] = 0;
    if (t < nb) { bptr[t + 1] = sbuf[t]; gcur[t] = sbuf[t] - c; }
}

// ===== bin edges into bucket-major order, LDS counting sort (valid. r2) ====
// emits 4B record ecv4 = (col<<16)|bf16(val) + 1B local-row erow.
__global__ __launch_bounds__(1024) void bin_edges(const int* __restrict__ rows,
                                                  const int* __restrict__ cols,
                                                  const float* __restrict__ vals,
                                                  int* __restrict__ gcur,
                                                  unsigned* __restrict__ ecv4,
                                                  unsigned char* __restrict__ erow,
                                                  int nE, int nb) {
    __shared__ unsigned secv[BIN_CHUNK];                   // 16 KB
    __shared__ unsigned short srow16[BIN_CHUNK];           // 8 KB
    __shared__ int hcnt[MAXNB], sbuf[MAXNB], loff[MAXNB], lcur[MAXNB], gbase[MAXNB];
    int t = threadIdx.x;
    int base = blockIdx.x * BIN_CHUNK;
    int nvalid = min(BIN_CHUNK, nE - base);
    hcnt[t] = 0;
    __syncthreads();
    for (int j = t; j < nvalid; j += 1024)            // A: local hist
        atomicAdd(&hcnt[rows[base + j] / BROWS], 1);
    __syncthreads();
    int myc = hcnt[t];                                 // B: scan
    sbuf[t] = myc;
    __syncthreads();
    for (int off = 1; off < 1024; off <<= 1) {
        int v = (t >= off) ? sbuf[t - off] : 0;
        __syncthreads();
        sbuf[t] += v;
        __syncthreads();
    }
    int excl = sbuf[t] - myc;
    loff[t] = excl;
    lcur[t] = excl;
    if (t < nb && myc > 0) gbase[t] = atomicAdd(&gcur[t], myc);  // C: reserve
    __syncthreads();
    for (int j = t; j < nvalid; j += 1024) {          // D: place into LDS
        int i = base + j;
        unsigned r = (unsigned)rows[i];
        int bk = (int)r / BROWS;
        int slot = atomicAdd(&lcur[bk], 1);
        secv[slot] = ((unsigned)cols[i] << 16) | f_to_bf16_bits(vals[i]);
        srow16[slot] = (unsigned short)r;
    }
    __syncthreads();
    for (int j = t; j < nvalid; j += 1024) {          // E: coalesced write-out
        unsigned r = srow16[j];
        int bk = (int)r / BROWS;
        int dst = gbase[bk] + (j - loff[bk]);
        ecv4[dst] = secv[j];
        erow[dst] = (unsigned char)(r & (BROWS - 1));
    }
}

// ============== SPMM on buckets (r2 structure, measured 198 us) ============
// One block (512 thr, 8 waves) per bucket of 64 rows. Wave w owns rows
// w*8..w*8+7. Half-wave edge split: lanes 0-31 process edges 4g..4g+3 of
// each 8-group, lanes 32-63 process edges 4g+4..4g+7; each lane covers 4
// output cols via one dwordx2 gather per edge. Cross-half combine is one
// __shfl_xor(32) per row at writeback. Segments padded to multiples of 8
// (pad record = 0 -> col 0, val +0.0 -> no contribution).
__global__ __launch_bounds__(512) void spmm_sorted(const int* __restrict__ bptr,
                                                   const unsigned* __restrict__ ecv4,
                                                   const unsigned char* __restrict__ erow,
                                                   const unsigned* __restrict__ hV,
                                                   float* __restrict__ out, int N) {
    __shared__ __align__(16) unsigned srec[SCHUNK + BROWS * 8];  // ~38 KB
    __shared__ int rcnt[BROWS], sbuf[BROWS], rptr[BROWS + 1], rcur[BROWS];
    int t = threadIdx.x;
    int b = blockIdx.x;
    int wave = t >> 6, lane = t & 63;
    int hf = lane >> 5;                                // half index 0/1
    int cl = lane & 31;                                // col block: 4*cl..4*cl+3
    int beg = bptr[b], end = bptr[b + 1];
    const uint2* hv2 = (const uint2*)hV;               // row stride = 32 uint2

    float4 acc[8];
#pragma unroll
    for (int j = 0; j < 8; ++j) acc[j] = make_float4(0.f, 0.f, 0.f, 0.f);

    for (int cb = beg; cb < end; cb += SCHUNK) {
        int nval = min(SCHUNK, end - cb);
        if (t < BROWS) rcnt[t] = 0;
        __syncthreads();
        for (int j = t; j < nval; j += 512)            // hist by local row
            atomicAdd(&rcnt[erow[cb + j]], 1);
        __syncthreads();
        int c = (t < BROWS) ? rcnt[t] : 0;             // scan PADDED counts
        int cp = (c + 7) & ~7;
        if (t < BROWS) sbuf[t] = cp;
        __syncthreads();
        for (int off = 1; off < BROWS; off <<= 1) {
            int add = (t < BROWS && t >= off) ? sbuf[t - off] : 0;
            __syncthreads();
            if (t < BROWS) sbuf[t] += add;
            __syncthreads();
        }
        if (t == 0) rptr[0] = 0;
        if (t < BROWS) { rptr[t + 1] = sbuf[t]; rcur[t] = sbuf[t] - cp; }
        __syncthreads();
        for (int j = t; j < nval; j += 512) {          // place sorted-by-row
            int rloc = erow[cb + j];
            int slot = atomicAdd(&rcur[rloc], 1);
            srec[slot] = ecv4[cb + j];
        }
        __syncthreads();
        if (t < BROWS) {                               // zero-fill pad slots
            int e0 = rcur[t];
            int e1 = rptr[t + 1];
            for (int k = e0; k < e1; ++k) srec[k] = 0u;
        }
        __syncthreads();
#pragma unroll
        for (int rr = 0; rr < 8; ++rr) {
            int rloc = wave * 8 + rr;
            int s = rptr[rloc];
            int ng = (rptr[rloc + 1] - s) >> 3;        // groups of 8 edges
            const uint4* sp = (const uint4*)&srec[s + 4 * hf];  // 16B-aligned
            float4 a = acc[rr];
            for (int g = 0; g < ng; ++g) {
                uint4 q = sp[2 * g];                   // this half's 4 records
                uint2 u0 = hv2[((q.x >> 16) << 5) | cl];
                uint2 u1 = hv2[((q.y >> 16) << 5) | cl];
                uint2 u2 = hv2[((q.z >> 16) << 5) | cl];
                uint2 u3 = hv2[((q.w >> 16) << 5) | cl];
                float v0 = bf16lo_to_f(q.x);
                float v1 = bf16lo_to_f(q.y);
                float v2 = bf16lo_to_f(q.z);
                float v3 = bf16lo_to_f(q.w);
                a.x += v0 * bf16lo_to_f(u0.x); a.y += v0 * bf16hi_to_f(u0.x);
                a.z += v0 * bf16lo_to_f(u0.y); a.w += v0 * bf16hi_to_f(u0.y);
                a.x += v1 * bf16lo_to_f(u1.x); a.y += v1 * bf16hi_to_f(u1.x);
                a.z += v1 * bf16lo_to_f(u1.y); a.w += v1 * bf16hi_to_f(u1.y);
                a.x += v2 * bf16lo_to_f(u2.x); a.y += v2 * bf16hi_to_f(u2.x);
                a.z += v2 * bf16lo_to_f(u2.y); a.w += v2 * bf16hi_to_f(u2.y);
                a.x += v3 * bf16lo_to_f(u3.x); a.y += v3 * bf16hi_to_f(u3.x);
                a.z += v3 * bf16lo_to_f(u3.y); a.w += v3 * bf16hi_to_f(u3.y);
            }
            acc[rr] = a;
        }
        __syncthreads();
    }
#pragma unroll
    for (int rr = 0; rr < 8; ++rr) {                   // combine halves + store
        float4 a = acc[rr];
        a.x += __shfl_xor(a.x, 32);
        a.y += __shfl_xor(a.y, 32);
        a.z += __shfl_xor(a.z, 32);
        a.w += __shfl_xor(a.w, 32);
        int gr = b * BROWS + wave * 8 + rr;
        if (hf == 0 && gr < N)
            ((float4*)(out + (size_t)gr * DOUT))[cl] = a;
    }
}

// =============== epilogue: out = relu(x@W + out) via MFMA ==================
// Same tile scheme as hv_gemm; K=256 in 8 steps; B = WT bf16 from global.
__global__ __launch_bounds__(256) void epi_xw(const float* __restrict__ x,
                                              const unsigned* __restrict__ WTu,
                                              float* __restrict__ out, int N) {
    __shared__ unsigned xs[64 * 20];
    int t = threadIdx.x;
    int r0 = blockIdx.x * 64;
    int w = t >> 6, l = t & 63;
    int wm = w >> 1, wn = w & 1;
    int lm = l & 15, lk = l >> 4;
    f32x4 acc[2][4];
#pragma unroll
    for (int i = 0; i < 2; ++i)
#pragma unroll
        for (int j = 0; j < 4; ++j) acc[i][j] = (f32x4){0.f, 0.f, 0.f, 0.f};

    int srow = min(r0 + (t >> 2), N - 1);
    const float* xrow = x + (size_t)srow * DIN + (t & 3) * 8;
    unsigned* xsw = &xs[(t >> 2) * 20 + (t & 3) * 4];

    for (int k0 = 0; k0 < DIN; k0 += 32) {
        float4 f0 = *(const float4*)(xrow + k0);
        float4 f1 = *(const float4*)(xrow + k0 + 4);
        ((uint4*)xsw)[0] = make_uint4(pack2(f0.x, f0.y), pack2(f0.z, f0.w),
                                      pack2(f1.x, f1.y), pack2(f1.z, f1.w));
        __syncthreads();
        FragU a[2], b[4];
#pragma unroll
        for (int i = 0; i < 2; ++i)
            a[i].q = *(const uint4*)&xs[(wm * 32 + i * 16 + lm) * 20 + lk * 4];
#pragma unroll
        for (int j = 0; j < 4; ++j)
            b[j].q = *(const uint4*)(WTu + (size_t)(wn * 64 + j * 16 + lm) * 128 +
                                     (k0 >> 1) + lk * 4);
#pragma unroll
        for (int i = 0; i < 2; ++i)
#pragma unroll
            for (int j = 0; j < 4; ++j)
                acc[i][j] = __builtin_amdgcn_mfma_f32_16x16x32_bf16(
                    a[i].f, b[j].f, acc[i][j], 0, 0, 0);
        __syncthreads();
    }
#pragma unroll
    for (int i = 0; i < 2; ++i)
#pragma unroll
        for (int j = 0; j < 4; ++j) {
            int gr0 = r0 + wm * 32 + i * 16 + lk * 4;
            int gc = wn * 64 + j * 16 + lm;
#pragma unroll
            for (int r = 0; r < 4; ++r) {
                int gr = gr0 + r;
                if (gr < N) {
                    size_t o = (size_t)gr * DOUT + gc;
                    out[o] = fmaxf(acc[i][j][r] + out[o], 0.f);
                }
            }
        }
}

// ==================== fallback path (ws too small / N too big) =============
__global__ void spmm_atomic(const int* __restrict__ rows,
                            const int* __restrict__ cols,
                            const float* __restrict__ vals,
                            const float* __restrict__ h,
                            float* __restrict__ S, int nEdges) {
    int wave = (int)((blockIdx.x * blockDim.x + threadIdx.x) >> 6);
    int lane = threadIdx.x & 63;
    if (wave >= nEdges) return;
    int r = rows[wave], c = cols[wave];
    float v = vals[wave];
    float2 hv = ((const float2*)(h + (size_t)c * DOUT))[lane];
    float* srow = S + (size_t)r * DOUT;
    atomicAdd(srow + 2 * lane,     v * hv.x);
    atomicAdd(srow + 2 * lane + 1, v * hv.y);
}

__global__ __launch_bounds__(256) void fused_out_full(const float* __restrict__ x,
                                                      const float* __restrict__ W,
                                                      const float* __restrict__ V,
                                                      float* __restrict__ out, int N) {
    __shared__ float xs[DIN];
    __shared__ float ss[DOUT];
    int r = blockIdx.x;
    int col = threadIdx.x & 127;
    if (threadIdx.x < 128) {
        float2 xv = ((const float2*)(x + (size_t)r * DIN))[col];
        xs[2 * col] = xv.x; xs[2 * col + 1] = xv.y;
        ss[col] = out[(size_t)r * DOUT + col];
    }
    __syncthreads();
    if (threadIdx.x >= 128) return;
    float acc = 0.f;
    for (int k = 0; k < DIN; ++k) acc += xs[k] * W[k * DOUT + col];
    for (int k = 0; k < DOUT; ++k) acc += ss[k] * V[k * DOUT + col];
    out[(size_t)r * DOUT + col] = fmaxf(acc, 0.f);
}

static inline size_t align256(size_t v) { return (v + 255) & ~(size_t)255; }

extern "C" void kernel_launch(void* const* d_in, const int* in_sizes, int n_in,
                              void* d_out, int out_size, void* d_ws, size_t ws_size,
                              hipStream_t stream) {
    const float* x    = (const float*)d_in[0];
    const float* h    = (const float*)d_in[1];
    const int*   rows = (const int*)d_in[2];
    const int*   cols = (const int*)d_in[3];
    const float* vals = (const float*)d_in[4];
    const float* W    = (const float*)d_in[5];
    const float* V    = (const float*)d_in[6];
    // d_in[7] (alpha): softmax over a size-1 axis == 1 -> dead.

    int nE = in_sizes[2];              // D*E = 6.4M
    int N  = in_sizes[1] / DOUT;       // 50000
    int nb = (N + BROWS - 1) / BROWS;  // 782 buckets
    float* out = (float*)d_out;

    // ws: hV[N*128 bf16] | WT[128x256 bf16] | VT[128x128 bf16] |
    //     gcnt | bptr | gcur | ecv4[nE u32] | erow[nE u8]
    size_t o_hV   = 0;
    size_t o_WT   = o_hV   + align256((size_t)N * DOUT * 2);
    size_t o_VT   = o_WT   + align256((size_t)128 * 256 * 2);
    size_t o_gcnt = o_VT   + align256((size_t)128 * 128 * 2);
    size_t o_bptr = o_gcnt + align256((size_t)nb * 4);
    size_t o_gcur = o_bptr + align256((size_t)(nb + 1) * 4);
    size_t o_ecv4 = o_gcur + align256((size_t)nb * 4);
    size_t o_erow = o_ecv4 + align256((size_t)nE * 4);
    size_t need   = o_erow + (size_t)nE;

    if (ws_size >= need && N < 65536 && nb <= MAXNB) {
        char* p = (char*)d_ws;
        unsigned short* hV = (unsigned short*)(p + o_hV);
        unsigned short* WT = (unsigned short*)(p + o_WT);
        unsigned short* VT = (unsigned short*)(p + o_VT);
        int*      gcnt = (int*)(p + o_gcnt);
        int*      bptr = (int*)(p + o_bptr);
        int*      gcur = (int*)(p + o_gcur);
        unsigned* ecv4 = (unsigned*)(p + o_ecv4);
        unsigned char* erow = (unsigned char*)(p + o_erow);

        conv_wv<<<128, 256, 0, stream>>>(W, V, WT, VT);
        hv_gemm<<<(N + 63) / 64, 256, 0, stream>>>(h, (const unsigned*)VT, hV, N);
        hipMemsetAsync(gcnt, 0, (size_t)nb * 4, stream);
        bucket_hist<<<1024, 256, 0, stream>>>(rows, gcnt, nE, nb);
        scan_buckets<<<1, 1024, 0, stream>>>(gcnt, bptr, gcur, nb);
        bin_edges<<<(nE + BIN_CHUNK - 1) / BIN_CHUNK, 1024, 0, stream>>>(
            rows, cols, vals, gcur, ecv4, erow, nE, nb);
        spmm_sorted<<<nb, 512, 0, stream>>>(bptr, ecv4, erow,
                                            (const unsigned*)hV, out, N);
        epi_xw<<<(N + 63) / 64, 256, 0, stream>>>(x, (const unsigned*)WT, out, N);
    } else {
        hipMemsetAsync(out, 0, (size_t)N * DOUT * 4, stream);
        spmm_atomic<<<(nE + 3) / 4, 256, 0, stream>>>(rows, cols, vals, h, out, nE);
        fused_out_full<<<N, 128, 0, stream>>>(x, W, V, out, N);
    }
}

// Round 6
// 491.263 us; speedup vs baseline: 1.4103x; 1.0163x over previous
//
#include <hip/hip_runtime.h>
#include <hip/hip_bf16.h>

#define DOUT 128
#define DIN  256
#define BROWS 64            // rows per bucket
#define MAXNB 1024          // bucket-scan width cap (nb = ceil(N/64) = 782)
#define BIN_CHUNK 4096      // edges per bin_edges block
#define SCHUNK 9216         // edges per spmm LDS chunk (mean 8184 + 11 sigma)

typedef __attribute__((ext_vector_type(8))) short bf16x8;
typedef __attribute__((ext_vector_type(4))) float f32x4;
union FragU { uint4 q; bf16x8 f; };

static __device__ __forceinline__ float bf16lo_to_f(unsigned u) {
    return __uint_as_float(u << 16);
}
static __device__ __forceinline__ float bf16hi_to_f(unsigned u) {
    return __uint_as_float(u & 0xffff0000u);
}
static __device__ __forceinline__ unsigned f_to_bf16_bits(float f) {
    unsigned u = __float_as_uint(f);               // RNE round to bf16
    return (u + 0x7fffu + ((u >> 16) & 1u)) >> 16;
}
static __device__ __forceinline__ unsigned pack2(float a, float b) {
    return f_to_bf16_bits(a) | (f_to_bf16_bits(b) << 16);
}

// ========== tiny: W^T, V^T -> bf16 (done once, 96 KB total) ================
__global__ __launch_bounds__(256) void conv_wv(const float* __restrict__ W,
                                               const float* __restrict__ V,
                                               unsigned short* __restrict__ WT,
                                               unsigned short* __restrict__ VT) {
    int n = blockIdx.x;                 // 0..127 output row (= col of W/V)
    int t = threadIdx.x;                // 0..255
    WT[n * 256 + t] = (unsigned short)f_to_bf16_bits(W[t * DOUT + n]);
    if (t < 128) VT[n * 128 + t] = (unsigned short)f_to_bf16_bits(V[t * DOUT + n]);
}

// ======================= hV = h @ V via MFMA (validated r5) ================
__global__ __launch_bounds__(256) void hv_gemm(const float* __restrict__ h,
                                               const unsigned* __restrict__ VTu,
                                               unsigned short* __restrict__ hV,
                                               int N) {
    __shared__ unsigned xs[64 * 20];
    int t = threadIdx.x;
    int r0 = blockIdx.x * 64;
    int w = t >> 6, l = t & 63;
    int wm = w >> 1, wn = w & 1;
    int lm = l & 15, lk = l >> 4;
    f32x4 acc[2][4];
#pragma unroll
    for (int i = 0; i < 2; ++i)
#pragma unroll
        for (int j = 0; j < 4; ++j) acc[i][j] = (f32x4){0.f, 0.f, 0.f, 0.f};

    int srow = min(r0 + (t >> 2), N - 1);
    const float* hrow = h + (size_t)srow * DOUT + (t & 3) * 8;
    unsigned* xsw = &xs[(t >> 2) * 20 + (t & 3) * 4];

    for (int k0 = 0; k0 < DOUT; k0 += 32) {
        float4 f0 = *(const float4*)(hrow + k0);
        float4 f1 = *(const float4*)(hrow + k0 + 4);
        ((uint4*)xsw)[0] = make_uint4(pack2(f0.x, f0.y), pack2(f0.z, f0.w),
                                      pack2(f1.x, f1.y), pack2(f1.z, f1.w));
        __syncthreads();
        FragU a[2], b[4];
#pragma unroll
        for (int i = 0; i < 2; ++i)
            a[i].q = *(const uint4*)&xs[(wm * 32 + i * 16 + lm) * 20 + lk * 4];
#pragma unroll
        for (int j = 0; j < 4; ++j)
            b[j].q = *(const uint4*)(VTu + (size_t)(wn * 64 + j * 16 + lm) * 64 +
                                     (k0 >> 1) + lk * 4);
#pragma unroll
        for (int i = 0; i < 2; ++i)
#pragma unroll
            for (int j = 0; j < 4; ++j)
                acc[i][j] = __builtin_amdgcn_mfma_f32_16x16x32_bf16(
                    a[i].f, b[j].f, acc[i][j], 0, 0, 0);
        __syncthreads();
    }
#pragma unroll
    for (int i = 0; i < 2; ++i)
#pragma unroll
        for (int j = 0; j < 4; ++j) {
            int gr0 = r0 + wm * 32 + i * 16 + lk * 4;
            int gc = wn * 64 + j * 16 + lm;
#pragma unroll
            for (int r = 0; r < 4; ++r) {
                int gr = gr0 + r;
                if (gr < N)
                    hV[(size_t)gr * DOUT + gc] =
                        (unsigned short)f_to_bf16_bits(acc[i][j][r]);
            }
        }
}

// ======================= bucket histogram (validated r5) ===================
__global__ void bucket_hist(const int* __restrict__ rows, int* __restrict__ gcnt,
                            int nE, int nb) {
    __shared__ int hc[MAXNB];
    for (int i = threadIdx.x; i < nb; i += blockDim.x) hc[i] = 0;
    __syncthreads();
    for (int i = blockIdx.x * blockDim.x + threadIdx.x; i < nE;
         i += gridDim.x * blockDim.x)
        atomicAdd(&hc[rows[i] / BROWS], 1);
    __syncthreads();
    for (int i = threadIdx.x; i < nb; i += blockDim.x)
        if (hc[i]) atomicAdd(&gcnt[i], hc[i]);
}

// ============ exclusive scan of bucket counts (shfl-scan r6) ===============
__global__ __launch_bounds__(1024) void scan_buckets(const int* __restrict__ gcnt,
                                                     int* __restrict__ bptr,
                                                     int* __restrict__ gcur, int nb) {
    __shared__ int wtot[16];
    int t = threadIdx.x;
    int c = (t < nb) ? gcnt[t] : 0;
    int v = c;
#pragma unroll
    for (int d = 1; d < 64; d <<= 1) {
        int u = __shfl_up(v, d);
        if ((t & 63) >= d) v += u;
    }
    if ((t & 63) == 63) wtot[t >> 6] = v;
    __syncthreads();
    if (t < 16) {
        int wv = wtot[t];
#pragma unroll
        for (int d = 1; d < 16; d <<= 1) {
            int u = __shfl_up(wv, d);
            if (t >= d) wv += u;
        }
        wtot[t] = wv;
    }
    __syncthreads();
    int incl = v + ((t >= 64) ? wtot[(t >> 6) - 1] : 0);
    if (t == 0) bptr[0] = 0;
    if (t < nb) { bptr[t + 1] = incl; gcur[t] = incl - c; }
}

// ===== bin edges into bucket-major order, LDS sort (shfl-scan r6) ==========
// emits 4B record ecv4 = (col<<16)|bf16(val) + 1B local-row erow.
__global__ __launch_bounds__(1024) void bin_edges(const int* __restrict__ rows,
                                                  const int* __restrict__ cols,
                                                  const float* __restrict__ vals,
                                                  int* __restrict__ gcur,
                                                  unsigned* __restrict__ ecv4,
                                                  unsigned char* __restrict__ erow,
                                                  int nE, int nb) {
    __shared__ unsigned secv[BIN_CHUNK];                   // 16 KB
    __shared__ unsigned short srow16[BIN_CHUNK];           // 8 KB
    __shared__ int hcnt[MAXNB], loff[MAXNB], lcur[MAXNB], gbase[MAXNB];
    __shared__ int wtot[16];
    int t = threadIdx.x;
    int base = blockIdx.x * BIN_CHUNK;
    int nvalid = min(BIN_CHUNK, nE - base);
    hcnt[t] = 0;
    __syncthreads();
    for (int j = t; j < nvalid; j += 1024)            // A: local hist
        atomicAdd(&hcnt[rows[base + j] / BROWS], 1);
    __syncthreads();
    int myc = hcnt[t];                                 // B: hierarchical scan
    int v = myc;
#pragma unroll
    for (int d = 1; d < 64; d <<= 1) {
        int u = __shfl_up(v, d);
        if ((t & 63) >= d) v += u;
    }
    if ((t & 63) == 63) wtot[t >> 6] = v;
    __syncthreads();
    if (t < 16) {
        int wv = wtot[t];
#pragma unroll
        for (int d = 1; d < 16; d <<= 1) {
            int u = __shfl_up(wv, d);
            if (t >= d) wv += u;
        }
        wtot[t] = wv;
    }
    __syncthreads();
    int excl = v - myc + ((t >= 64) ? wtot[(t >> 6) - 1] : 0);
    loff[t] = excl;
    lcur[t] = excl;
    if (t < nb && myc > 0) gbase[t] = atomicAdd(&gcur[t], myc);  // C: reserve
    __syncthreads();
    for (int j = t; j < nvalid; j += 1024) {          // D: place into LDS
        int i = base + j;
        unsigned r = (unsigned)rows[i];
        int bk = (int)r / BROWS;
        int slot = atomicAdd(&lcur[bk], 1);
        secv[slot] = ((unsigned)cols[i] << 16) | f_to_bf16_bits(vals[i]);
        srow16[slot] = (unsigned short)r;
    }
    __syncthreads();
    for (int j = t; j < nvalid; j += 1024) {          // E: coalesced write-out
        unsigned r = srow16[j];
        int bk = (int)r / BROWS;
        int dst = gbase[bk] + (j - loff[bk]);
        ecv4[dst] = secv[j];
        erow[dst] = (unsigned char)(r & (BROWS - 1));
    }
}

// ========= SPMM (r2 structure, 198us) + FUSED epilogue relu(x@W + S) =======
// Phase 1: exactly the validated r2 chunk loop -> acc float4[8]/lane.
// Then S staged into LDS (aliasing the dead srec buffer) and phase 2 runs
// the 64x128 x@W MFMA tile in-block, storing out exactly once. Saves the
// epi_xw launch and the 51.2 MB out write+read round trip.
__global__ __launch_bounds__(512) void spmm_epi(const int* __restrict__ bptr,
                                                const unsigned* __restrict__ ecv4,
                                                const unsigned char* __restrict__ erow,
                                                const unsigned* __restrict__ hV,
                                                const float* __restrict__ x,
                                                const unsigned* __restrict__ WTu,
                                                float* __restrict__ out, int N) {
    __shared__ __align__(16) unsigned srec[SCHUNK + BROWS * 8];  // 38912 B
    __shared__ int rcnt[BROWS], rptr[BROWS + 1], rcur[BROWS];
    int t = threadIdx.x;
    int b = blockIdx.x;
    int wave = t >> 6, lane = t & 63;
    int hf = lane >> 5;                                // half index 0/1
    int cl = lane & 31;                                // col block: 4*cl..4*cl+3
    int beg = bptr[b], end = bptr[b + 1];
    const uint2* hv2 = (const uint2*)hV;               // row stride = 32 uint2

    float4 acc[8];
#pragma unroll
    for (int j = 0; j < 8; ++j) acc[j] = make_float4(0.f, 0.f, 0.f, 0.f);

    for (int cb = beg; cb < end; cb += SCHUNK) {
        int nval = min(SCHUNK, end - cb);
        if (t < BROWS) rcnt[t] = 0;
        __syncthreads();
        for (int j = t; j < nval; j += 512)            // hist by local row
            atomicAdd(&rcnt[erow[cb + j]], 1);
        __syncthreads();
        if (wave == 0) {                               // wave-0 shfl scan
            int c = rcnt[lane];
            int cp = (c + 7) & ~7;
            int v = cp;
#pragma unroll
            for (int d = 1; d < 64; d <<= 1) {
                int u = __shfl_up(v, d);
                if (lane >= d) v += u;
            }
            rptr[lane + 1] = v;
            rcur[lane] = v - cp;
            if (lane == 0) rptr[0] = 0;
        }
        __syncthreads();
        for (int j = t; j < nval; j += 512) {          // place sorted-by-row
            int rloc = erow[cb + j];
            int slot = atomicAdd(&rcur[rloc], 1);
            srec[slot] = ecv4[cb + j];
        }
        __syncthreads();
        if (t < BROWS) {                               // zero-fill pad slots
            int e0 = rcur[t];
            int e1 = rptr[t + 1];
            for (int k = e0; k < e1; ++k) srec[k] = 0u;
        }
        __syncthreads();
#pragma unroll
        for (int rr = 0; rr < 8; ++rr) {
            int rloc = wave * 8 + rr;
            int s = rptr[rloc];
            int ng = (rptr[rloc + 1] - s) >> 3;        // groups of 8 edges
            const uint4* sp = (const uint4*)&srec[s + 4 * hf];  // 16B-aligned
            float4 a = acc[rr];
            for (int g = 0; g < ng; ++g) {
                uint4 q = sp[2 * g];                   // this half's 4 records
                uint2 u0 = hv2[((q.x >> 16) << 5) | cl];
                uint2 u1 = hv2[((q.y >> 16) << 5) | cl];
                uint2 u2 = hv2[((q.z >> 16) << 5) | cl];
                uint2 u3 = hv2[((q.w >> 16) << 5) | cl];
                float v0 = bf16lo_to_f(q.x);
                float v1 = bf16lo_to_f(q.y);
                float v2 = bf16lo_to_f(q.z);
                float v3 = bf16lo_to_f(q.w);
                a.x += v0 * bf16lo_to_f(u0.x); a.y += v0 * bf16hi_to_f(u0.x);
                a.z += v0 * bf16lo_to_f(u0.y); a.w += v0 * bf16hi_to_f(u0.y);
                a.x += v1 * bf16lo_to_f(u1.x); a.y += v1 * bf16hi_to_f(u1.x);
                a.z += v1 * bf16lo_to_f(u1.y); a.w += v1 * bf16hi_to_f(u1.y);
                a.x += v2 * bf16lo_to_f(u2.x); a.y += v2 * bf16hi_to_f(u2.x);
                a.z += v2 * bf16lo_to_f(u2.y); a.w += v2 * bf16hi_to_f(u2.y);
                a.x += v3 * bf16lo_to_f(u3.x); a.y += v3 * bf16hi_to_f(u3.x);
                a.z += v3 * bf16lo_to_f(u3.y); a.w += v3 * bf16hi_to_f(u3.y);
            }
            acc[rr] = a;
        }
        __syncthreads();
    }

    // ---- stage S = A@hV block into LDS (aliases srec; loop ended w/ barrier)
    float* Sbuf = (float*)srec;                        // [64][132] f32, 33792 B
#pragma unroll
    for (int rr = 0; rr < 8; ++rr) {
        float4 a = acc[rr];
        a.x += __shfl_xor(a.x, 32);
        a.y += __shfl_xor(a.y, 32);
        a.z += __shfl_xor(a.z, 32);
        a.w += __shfl_xor(a.w, 32);
        if (hf == 0)
            *(float4*)&Sbuf[(wave * 8 + rr) * 132 + 4 * cl] = a;
    }
    __syncthreads();

    // ---- phase 2: out = relu(x@W + S), 64x128 tile, 8 waves (4m x 2n) ----
    unsigned* xs = srec + 64 * 132;                    // u32 [64][18], 4608 B
    int wm = wave >> 1, wn = wave & 1;
    int lm = lane & 15, lk = lane >> 4;
    f32x4 acc4[4];
#pragma unroll
    for (int j = 0; j < 4; ++j) acc4[j] = (f32x4){0.f, 0.f, 0.f, 0.f};

    int r0 = b * BROWS;
    int srow = min(r0 + (t >> 3), N - 1);
    const float* xrow = x + (size_t)srow * DIN + (t & 7) * 4;
    unsigned* xsw = &xs[(t >> 3) * 18 + (t & 7) * 2];

    for (int k0 = 0; k0 < DIN; k0 += 32) {
        float4 f = *(const float4*)(xrow + k0);
        xsw[0] = pack2(f.x, f.y);
        xsw[1] = pack2(f.z, f.w);
        __syncthreads();
        FragU a;
        a.q = *(const uint4*)&xs[(wm * 16 + lm) * 18 + lk * 4];
#pragma unroll
        for (int j = 0; j < 4; ++j) {
            FragU bb;
            bb.q = *(const uint4*)(WTu + (size_t)(wn * 64 + j * 16 + lm) * 128 +
                                   (k0 >> 1) + lk * 4);
            acc4[j] = __builtin_amdgcn_mfma_f32_16x16x32_bf16(
                a.f, bb.f, acc4[j], 0, 0, 0);
        }
        __syncthreads();
    }
#pragma unroll
    for (int j = 0; j < 4; ++j) {
        int gc = wn * 64 + j * 16 + lm;
#pragma unroll
        for (int r = 0; r < 4; ++r) {
            int lr = wm * 16 + 4 * lk + r;
            int gr = r0 + lr;
            if (gr < N)
                out[(size_t)gr * DOUT + gc] =
                    fmaxf(acc4[j][r] + Sbuf[lr * 132 + gc], 0.f);
        }
    }
}

// ==================== fallback path (ws too small / N too big) =============
__global__ void spmm_atomic(const int* __restrict__ rows,
                            const int* __restrict__ cols,
                            const float* __restrict__ vals,
                            const float* __restrict__ h,
                            float* __restrict__ S, int nEdges) {
    int wave = (int)((blockIdx.x * blockDim.x + threadIdx.x) >> 6);
    int lane = threadIdx.x & 63;
    if (wave >= nEdges) return;
    int r = rows[wave], c = cols[wave];
    float v = vals[wave];
    float2 hv = ((const float2*)(h + (size_t)c * DOUT))[lane];
    float* srow = S + (size_t)r * DOUT;
    atomicAdd(srow + 2 * lane,     v * hv.x);
    atomicAdd(srow + 2 * lane + 1, v * hv.y);
}

__global__ __launch_bounds__(256) void fused_out_full(const float* __restrict__ x,
                                                      const float* __restrict__ W,
                                                      const float* __restrict__ V,
                                                      float* __restrict__ out, int N) {
    __shared__ float xs[DIN];
    __shared__ float ss[DOUT];
    int r = blockIdx.x;
    int col = threadIdx.x & 127;
    if (threadIdx.x < 128) {
        float2 xv = ((const float2*)(x + (size_t)r * DIN))[col];
        xs[2 * col] = xv.x; xs[2 * col + 1] = xv.y;
        ss[col] = out[(size_t)r * DOUT + col];
    }
    __syncthreads();
    if (threadIdx.x >= 128) return;
    float acc = 0.f;
    for (int k = 0; k < DIN; ++k) acc += xs[k] * W[k * DOUT + col];
    for (int k = 0; k < DOUT; ++k) acc += ss[k] * V[k * DOUT + col];
    out[(size_t)r * DOUT + col] = fmaxf(acc, 0.f);
}

static inline size_t align256(size_t v) { return (v + 255) & ~(size_t)255; }

extern "C" void kernel_launch(void* const* d_in, const int* in_sizes, int n_in,
                              void* d_out, int out_size, void* d_ws, size_t ws_size,
                              hipStream_t stream) {
    const float* x    = (const float*)d_in[0];
    const float* h    = (const float*)d_in[1];
    const int*   rows = (const int*)d_in[2];
    const int*   cols = (const int*)d_in[3];
    const float* vals = (const float*)d_in[4];
    const float* W    = (const float*)d_in[5];
    const float* V    = (const float*)d_in[6];
    // d_in[7] (alpha): softmax over a size-1 axis == 1 -> dead.

    int nE = in_sizes[2];              // D*E = 6.4M
    int N  = in_sizes[1] / DOUT;       // 50000
    int nb = (N + BROWS - 1) / BROWS;  // 782 buckets
    float* out = (float*)d_out;

    // ws: hV[N*128 bf16] | WT[128x256 bf16] | VT[128x128 bf16] |
    //     gcnt | bptr | gcur | ecv4[nE u32] | erow[nE u8]
    size_t o_hV   = 0;
    size_t o_WT   = o_hV   + align256((size_t)N * DOUT * 2);
    size_t o_VT   = o_WT   + align256((size_t)128 * 256 * 2);
    size_t o_gcnt = o_VT   + align256((size_t)128 * 128 * 2);
    size_t o_bptr = o_gcnt + align256((size_t)nb * 4);
    size_t o_gcur = o_bptr + align256((size_t)(nb + 1) * 4);
    size_t o_ecv4 = o_gcur + align256((size_t)nb * 4);
    size_t o_erow = o_ecv4 + align256((size_t)nE * 4);
    size_t need   = o_erow + (size_t)nE;

    if (ws_size >= need && N < 65536 && nb <= MAXNB) {
        char* p = (char*)d_ws;
        unsigned short* hV = (unsigned short*)(p + o_hV);
        unsigned short* WT = (unsigned short*)(p + o_WT);
        unsigned short* VT = (unsigned short*)(p + o_VT);
        int*      gcnt = (int*)(p + o_gcnt);
        int*      bptr = (int*)(p + o_bptr);
        int*      gcur = (int*)(p + o_gcur);
        unsigned* ecv4 = (unsigned*)(p + o_ecv4);
        unsigned char* erow = (unsigned char*)(p + o_erow);

        conv_wv<<<128, 256, 0, stream>>>(W, V, WT, VT);
        hv_gemm<<<(N + 63) / 64, 256, 0, stream>>>(h, (const unsigned*)VT, hV, N);
        hipMemsetAsync(gcnt, 0, (size_t)nb * 4, stream);
        bucket_hist<<<1024, 256, 0, stream>>>(rows, gcnt, nE, nb);
        scan_buckets<<<1, 1024, 0, stream>>>(gcnt, bptr, gcur, nb);
        bin_edges<<<(nE + BIN_CHUNK - 1) / BIN_CHUNK, 1024, 0, stream>>>(
            rows, cols, vals, gcur, ecv4, erow, nE, nb);
        spmm_epi<<<nb, 512, 0, stream>>>(bptr, ecv4, erow, (const unsigned*)hV,
                                         x, (const unsigned*)WT, out, N);
    } else {
        hipMemsetAsync(out, 0, (size_t)N * DOUT * 4, stream);
        spmm_atomic<<<(nE + 3) / 4, 256, 0, stream>>>(rows, cols, vals, h, out, nE);
        fused_out_full<<<N, 128, 0, stream>>>(x, W, V, out, N);
    }
}

// Round 7
// 472.448 us; speedup vs baseline: 1.4664x; 1.0398x over previous
//
#include <hip/hip_runtime.h>
#include <hip/hip_bf16.h>

#define DOUT 128
#define DIN  256
#define BROWS 64            // rows per bucket
#define MAXNB 1024          // bucket-scan width cap (nb = ceil(N/64) = 782)
#define BIN_CHUNK 4096      // edges per bin_edges block
#define SCHUNK 9216         // edges per spmm LDS chunk (mean 8184 + 11 sigma)
#define NREG 4              // hV row regions (3.2 MB each -> per-XCD L2)
#define SBINS (NREG * BROWS)

typedef __attribute__((ext_vector_type(8))) short bf16x8;
typedef __attribute__((ext_vector_type(4))) float f32x4;
union FragU { uint4 q; bf16x8 f; };

static __device__ __forceinline__ float bf16lo_to_f(unsigned u) {
    return __uint_as_float(u << 16);
}
static __device__ __forceinline__ float bf16hi_to_f(unsigned u) {
    return __uint_as_float(u & 0xffff0000u);
}
static __device__ __forceinline__ unsigned f_to_bf16_bits(float f) {
    unsigned u = __float_as_uint(f);               // RNE round to bf16
    return (u + 0x7fffu + ((u >> 16) & 1u)) >> 16;
}
static __device__ __forceinline__ unsigned pack2(float a, float b) {
    return f_to_bf16_bits(a) | (f_to_bf16_bits(b) << 16);
}

// ========== tiny: W^T, V^T -> bf16 (done once, 96 KB total) ================
__global__ __launch_bounds__(256) void conv_wv(const float* __restrict__ W,
                                               const float* __restrict__ V,
                                               unsigned short* __restrict__ WT,
                                               unsigned short* __restrict__ VT) {
    int n = blockIdx.x;                 // 0..127 output row (= col of W/V)
    int t = threadIdx.x;                // 0..255
    WT[n * 256 + t] = (unsigned short)f_to_bf16_bits(W[t * DOUT + n]);
    if (t < 128) VT[n * 128 + t] = (unsigned short)f_to_bf16_bits(V[t * DOUT + n]);
}

// ======================= hV = h @ V via MFMA (validated r5) ================
__global__ __launch_bounds__(256) void hv_gemm(const float* __restrict__ h,
                                               const unsigned* __restrict__ VTu,
                                               unsigned short* __restrict__ hV,
                                               int N) {
    __shared__ unsigned xs[64 * 20];
    int t = threadIdx.x;
    int r0 = blockIdx.x * 64;
    int w = t >> 6, l = t & 63;
    int wm = w >> 1, wn = w & 1;
    int lm = l & 15, lk = l >> 4;
    f32x4 acc[2][4];
#pragma unroll
    for (int i = 0; i < 2; ++i)
#pragma unroll
        for (int j = 0; j < 4; ++j) acc[i][j] = (f32x4){0.f, 0.f, 0.f, 0.f};

    int srow = min(r0 + (t >> 2), N - 1);
    const float* hrow = h + (size_t)srow * DOUT + (t & 3) * 8;
    unsigned* xsw = &xs[(t >> 2) * 20 + (t & 3) * 4];

    for (int k0 = 0; k0 < DOUT; k0 += 32) {
        float4 f0 = *(const float4*)(hrow + k0);
        float4 f1 = *(const float4*)(hrow + k0 + 4);
        ((uint4*)xsw)[0] = make_uint4(pack2(f0.x, f0.y), pack2(f0.z, f0.w),
                                      pack2(f1.x, f1.y), pack2(f1.z, f1.w));
        __syncthreads();
        FragU a[2], b[4];
#pragma unroll
        for (int i = 0; i < 2; ++i)
            a[i].q = *(const uint4*)&xs[(wm * 32 + i * 16 + lm) * 20 + lk * 4];
#pragma unroll
        for (int j = 0; j < 4; ++j)
            b[j].q = *(const uint4*)(VTu + (size_t)(wn * 64 + j * 16 + lm) * 64 +
                                     (k0 >> 1) + lk * 4);
#pragma unroll
        for (int i = 0; i < 2; ++i)
#pragma unroll
            for (int j = 0; j < 4; ++j)
                acc[i][j] = __builtin_amdgcn_mfma_f32_16x16x32_bf16(
                    a[i].f, b[j].f, acc[i][j], 0, 0, 0);
        __syncthreads();
    }
#pragma unroll
    for (int i = 0; i < 2; ++i)
#pragma unroll
        for (int j = 0; j < 4; ++j) {
            int gr0 = r0 + wm * 32 + i * 16 + lk * 4;
            int gc = wn * 64 + j * 16 + lm;
#pragma unroll
            for (int r = 0; r < 4; ++r) {
                int gr = gr0 + r;
                if (gr < N)
                    hV[(size_t)gr * DOUT + gc] =
                        (unsigned short)f_to_bf16_bits(acc[i][j][r]);
            }
        }
}

// ======================= bucket histogram (validated r5) ===================
__global__ void bucket_hist(const int* __restrict__ rows, int* __restrict__ gcnt,
                            int nE, int nb) {
    __shared__ int hc[MAXNB];
    for (int i = threadIdx.x; i < nb; i += blockDim.x) hc[i] = 0;
    __syncthreads();
    for (int i = blockIdx.x * blockDim.x + threadIdx.x; i < nE;
         i += gridDim.x * blockDim.x)
        atomicAdd(&hc[rows[i] / BROWS], 1);
    __syncthreads();
    for (int i = threadIdx.x; i < nb; i += blockDim.x)
        if (hc[i]) atomicAdd(&gcnt[i], hc[i]);
}

// ============ exclusive scan of bucket counts (shfl-scan r6) ===============
__global__ __launch_bounds__(1024) void scan_buckets(const int* __restrict__ gcnt,
                                                     int* __restrict__ bptr,
                                                     int* __restrict__ gcur, int nb) {
    __shared__ int wtot[16];
    int t = threadIdx.x;
    int c = (t < nb) ? gcnt[t] : 0;
    int v = c;
#pragma unroll
    for (int d = 1; d < 64; d <<= 1) {
        int u = __shfl_up(v, d);
        if ((t & 63) >= d) v += u;
    }
    if ((t & 63) == 63) wtot[t >> 6] = v;
    __syncthreads();
    if (t < 16) {
        int wv = wtot[t];
#pragma unroll
        for (int d = 1; d < 16; d <<= 1) {
            int u = __shfl_up(wv, d);
            if (t >= d) wv += u;
        }
        wtot[t] = wv;
    }
    __syncthreads();
    int incl = v + ((t >= 64) ? wtot[(t >> 6) - 1] : 0);
    if (t == 0) bptr[0] = 0;
    if (t < nb) { bptr[t + 1] = incl; gcur[t] = incl - c; }
}

// ===== bin edges into bucket-major order (shfl-scan r6) ====================
// r7: erow byte now carries (col_region<<6) | local_row. Region = which
// quarter of hV's rows the gather hits (partition need not be exact --
// any consistent assignment is correct; it only steers locality).
__global__ __launch_bounds__(1024) void bin_edges(const int* __restrict__ rows,
                                                  const int* __restrict__ cols,
                                                  const float* __restrict__ vals,
                                                  int* __restrict__ gcur,
                                                  unsigned* __restrict__ ecv4,
                                                  unsigned char* __restrict__ erow,
                                                  int nE, int nb, float regInv) {
    __shared__ unsigned secv[BIN_CHUNK];                   // 16 KB
    __shared__ unsigned short srow16[BIN_CHUNK];           // 8 KB
    __shared__ unsigned char sreg[BIN_CHUNK];              // 4 KB
    __shared__ int hcnt[MAXNB], loff[MAXNB], lcur[MAXNB], gbase[MAXNB];
    __shared__ int wtot[16];
    int t = threadIdx.x;
    int base = blockIdx.x * BIN_CHUNK;
    int nvalid = min(BIN_CHUNK, nE - base);
    hcnt[t] = 0;
    __syncthreads();
    for (int j = t; j < nvalid; j += 1024)            // A: local hist
        atomicAdd(&hcnt[rows[base + j] / BROWS], 1);
    __syncthreads();
    int myc = hcnt[t];                                 // B: hierarchical scan
    int v = myc;
#pragma unroll
    for (int d = 1; d < 64; d <<= 1) {
        int u = __shfl_up(v, d);
        if ((t & 63) >= d) v += u;
    }
    if ((t & 63) == 63) wtot[t >> 6] = v;
    __syncthreads();
    if (t < 16) {
        int wv = wtot[t];
#pragma unroll
        for (int d = 1; d < 16; d <<= 1) {
            int u = __shfl_up(wv, d);
            if (t >= d) wv += u;
        }
        wtot[t] = wv;
    }
    __syncthreads();
    int excl = v - myc + ((t >= 64) ? wtot[(t >> 6) - 1] : 0);
    loff[t] = excl;
    lcur[t] = excl;
    if (t < nb && myc > 0) gbase[t] = atomicAdd(&gcur[t], myc);  // C: reserve
    __syncthreads();
    for (int j = t; j < nvalid; j += 1024) {          // D: place into LDS
        int i = base + j;
        unsigned r = (unsigned)rows[i];
        int col = cols[i];
        int bk = (int)r / BROWS;
        int reg = min(NREG - 1, (int)((float)col * regInv));
        int slot = atomicAdd(&lcur[bk], 1);
        secv[slot] = ((unsigned)col << 16) | f_to_bf16_bits(vals[i]);
        srow16[slot] = (unsigned short)r;
        sreg[slot] = (unsigned char)reg;
    }
    __syncthreads();
    for (int j = t; j < nvalid; j += 1024) {          // E: coalesced write-out
        unsigned r = srow16[j];
        int bk = (int)r / BROWS;
        int dst = gbase[bk] + (j - loff[bk]);
        ecv4[dst] = secv[j];
        erow[dst] = (unsigned char)((sreg[j] << 6) | (r & (BROWS - 1)));
    }
}

// ========= SPMM + fused epilogue, r7: col-region phased walk ===============
// Per chunk: counting sort by 256 bins = (col_region<<6)|local_row (segments
// padded to 8). Walk runs 4 phases; phase p touches only the contiguous
// 3.2 MB hV slab of region p (per-XCD L2-resident) while keeping the FULL
// 256 B/edge gather and the validated r2 lane mapping: half-wave edge split,
// each lane covers 4 output cols, acc[8] persists across phases & chunks
// (cols identical in every phase -- only edge ORDER changed). Each edge is
// processed exactly once. Then fused out = relu(x@W + S) as r6.
__global__ __launch_bounds__(512) void spmm_epi(const int* __restrict__ bptr,
                                                const unsigned* __restrict__ ecv4,
                                                const unsigned char* __restrict__ erow,
                                                const unsigned* __restrict__ hV,
                                                const float* __restrict__ x,
                                                const unsigned* __restrict__ WTu,
                                                float* __restrict__ out, int N) {
    __shared__ __align__(16) unsigned srec[SCHUNK + SBINS * 8];  // 45056 B
    __shared__ int rcnt[SBINS], rptr[SBINS + 1], rcur[SBINS];
    int t = threadIdx.x;
    int b = blockIdx.x;
    int wave = t >> 6, lane = t & 63;
    int hf = lane >> 5;                                // half index 0/1
    int cl = lane & 31;                                // col block: 4*cl..4*cl+3
    int beg = bptr[b], end = bptr[b + 1];
    const uint2* hv2 = (const uint2*)hV;               // row stride = 32 uint2

    float4 acc[8];
#pragma unroll
    for (int j = 0; j < 8; ++j) acc[j] = make_float4(0.f, 0.f, 0.f, 0.f);

    for (int cb = beg; cb < end; cb += SCHUNK) {
        int nval = min(SCHUNK, end - cb);
        if (t < SBINS) rcnt[t] = 0;
        __syncthreads();
        for (int j = t; j < nval; j += 512)            // hist by (reg,row) bin
            atomicAdd(&rcnt[erow[cb + j]], 1);
        __syncthreads();
        if (wave == 0) {                               // 256-bin scan, 4/lane
            int b0 = 4 * lane;
            int c0 = (rcnt[b0] + 7) & ~7;
            int c1 = (rcnt[b0 + 1] + 7) & ~7;
            int c2 = (rcnt[b0 + 2] + 7) & ~7;
            int c3 = (rcnt[b0 + 3] + 7) & ~7;
            int s1 = c0 + c1, s2 = s1 + c2, tot = s2 + c3;
            int v = tot;
#pragma unroll
            for (int d = 1; d < 64; d <<= 1) {
                int u = __shfl_up(v, d);
                if (lane >= d) v += u;
            }
            int base0 = v - tot;
            rptr[b0 + 1] = base0 + c0;
            rptr[b0 + 2] = base0 + s1;
            rptr[b0 + 3] = base0 + s2;
            rptr[b0 + 4] = base0 + tot;
            rcur[b0]     = base0;
            rcur[b0 + 1] = base0 + c0;
            rcur[b0 + 2] = base0 + s1;
            rcur[b0 + 3] = base0 + s2;
            if (lane == 0) rptr[0] = 0;
        }
        __syncthreads();
        for (int j = t; j < nval; j += 512) {          // place sorted-by-bin
            int bin = erow[cb + j];
            int slot = atomicAdd(&rcur[bin], 1);
            srec[slot] = ecv4[cb + j];
        }
        __syncthreads();
        if (t < SBINS) {                               // zero-fill pad slots
            int e0 = rcur[t];
            int e1 = rptr[t + 1];
            for (int k = e0; k < e1; ++k) srec[k] = 0u;
        }
        __syncthreads();
#pragma unroll
        for (int p = 0; p < NREG; ++p) {               // L2-slab phases
#pragma unroll
            for (int rr = 0; rr < 8; ++rr) {
                int bin = (p << 6) | (wave << 3) | rr;
                int s = rptr[bin];
                int ng = (rptr[bin + 1] - s) >> 3;     // groups of 8 edges
                const uint4* sp = (const uint4*)&srec[s + 4 * hf];
                float4 a = acc[rr];
                for (int g = 0; g < ng; ++g) {
                    uint4 q = sp[2 * g];               // this half's 4 records
                    uint2 u0 = hv2[((q.x >> 16) << 5) | cl];
                    uint2 u1 = hv2[((q.y >> 16) << 5) | cl];
                    uint2 u2 = hv2[((q.z >> 16) << 5) | cl];
                    uint2 u3 = hv2[((q.w >> 16) << 5) | cl];
                    float v0 = bf16lo_to_f(q.x);
                    float v1 = bf16lo_to_f(q.y);
                    float v2 = bf16lo_to_f(q.z);
                    float v3 = bf16lo_to_f(q.w);
                    a.x += v0 * bf16lo_to_f(u0.x); a.y += v0 * bf16hi_to_f(u0.x);
                    a.z += v0 * bf16lo_to_f(u0.y); a.w += v0 * bf16hi_to_f(u0.y);
                    a.x += v1 * bf16lo_to_f(u1.x); a.y += v1 * bf16hi_to_f(u1.x);
                    a.z += v1 * bf16lo_to_f(u1.y); a.w += v1 * bf16hi_to_f(u1.y);
                    a.x += v2 * bf16lo_to_f(u2.x); a.y += v2 * bf16hi_to_f(u2.x);
                    a.z += v2 * bf16lo_to_f(u2.y); a.w += v2 * bf16hi_to_f(u2.y);
                    a.x += v3 * bf16lo_to_f(u3.x); a.y += v3 * bf16hi_to_f(u3.x);
                    a.z += v3 * bf16lo_to_f(u3.y); a.w += v3 * bf16hi_to_f(u3.y);
                }
                acc[rr] = a;
            }
            __syncthreads();                           // phase coherence
        }
    }

    // ---- stage S = A@hV block into LDS (aliases srec; loop ended w/ barrier)
    float* Sbuf = (float*)srec;                        // [64][132] f32, 33792 B
#pragma unroll
    for (int rr = 0; rr < 8; ++rr) {
        float4 a = acc[rr];
        a.x += __shfl_xor(a.x, 32);
        a.y += __shfl_xor(a.y, 32);
        a.z += __shfl_xor(a.z, 32);
        a.w += __shfl_xor(a.w, 32);
        if (hf == 0)
            *(float4*)&Sbuf[(wave * 8 + rr) * 132 + 4 * cl] = a;
    }
    __syncthreads();

    // ---- phase 2: out = relu(x@W + S), 64x128 tile, 8 waves (4m x 2n) ----
    unsigned* xs = srec + 64 * 132;                    // u32 [64][18], 4608 B
    int wm = wave >> 1, wn = wave & 1;
    int lm = lane & 15, lk = lane >> 4;
    f32x4 acc4[4];
#pragma unroll
    for (int j = 0; j < 4; ++j) acc4[j] = (f32x4){0.f, 0.f, 0.f, 0.f};

    int r0 = b * BROWS;
    int srow = min(r0 + (t >> 3), N - 1);
    const float* xrow = x + (size_t)srow * DIN + (t & 7) * 4;
    unsigned* xsw = &xs[(t >> 3) * 18 + (t & 7) * 2];

    for (int k0 = 0; k0 < DIN; k0 += 32) {
        float4 f = *(const float4*)(xrow + k0);
        xsw[0] = pack2(f.x, f.y);
        xsw[1] = pack2(f.z, f.w);
        __syncthreads();
        FragU a;
        a.q = *(const uint4*)&xs[(wm * 16 + lm) * 18 + lk * 4];
#pragma unroll
        for (int j = 0; j < 4; ++j) {
            FragU bb;
            bb.q = *(const uint4*)(WTu + (size_t)(wn * 64 + j * 16 + lm) * 128 +
                                   (k0 >> 1) + lk * 4);
            acc4[j] = __builtin_amdgcn_mfma_f32_16x16x32_bf16(
                a.f, bb.f, acc4[j], 0, 0, 0);
        }
        __syncthreads();
    }
#pragma unroll
    for (int j = 0; j < 4; ++j) {
        int gc = wn * 64 + j * 16 + lm;
#pragma unroll
        for (int r = 0; r < 4; ++r) {
            int lr = wm * 16 + 4 * lk + r;
            int gr = r0 + lr;
            if (gr < N)
                out[(size_t)gr * DOUT + gc] =
                    fmaxf(acc4[j][r] + Sbuf[lr * 132 + gc], 0.f);
        }
    }
}

// ==================== fallback path (ws too small / N too big) =============
__global__ void spmm_atomic(const int* __restrict__ rows,
                            const int* __restrict__ cols,
                            const float* __restrict__ vals,
                            const float* __restrict__ h,
                            float* __restrict__ S, int nEdges) {
    int wave = (int)((blockIdx.x * blockDim.x + threadIdx.x) >> 6);
    int lane = threadIdx.x & 63;
    if (wave >= nEdges) return;
    int r = rows[wave], c = cols[wave];
    float v = vals[wave];
    float2 hv = ((const float2*)(h + (size_t)c * DOUT))[lane];
    float* srow = S + (size_t)r * DOUT;
    atomicAdd(srow + 2 * lane,     v * hv.x);
    atomicAdd(srow + 2 * lane + 1, v * hv.y);
}

__global__ __launch_bounds__(256) void fused_out_full(const float* __restrict__ x,
                                                      const float* __restrict__ W,
                                                      const float* __restrict__ V,
                                                      float* __restrict__ out, int N) {
    __shared__ float xs[DIN];
    __shared__ float ss[DOUT];
    int r = blockIdx.x;
    int col = threadIdx.x & 127;
    if (threadIdx.x < 128) {
        float2 xv = ((const float2*)(x + (size_t)r * DIN))[col];
        xs[2 * col] = xv.x; xs[2 * col + 1] = xv.y;
        ss[col] = out[(size_t)r * DOUT + col];
    }
    __syncthreads();
    if (threadIdx.x >= 128) return;
    float acc = 0.f;
    for (int k = 0; k < DIN; ++k) acc += xs[k] * W[k * DOUT + col];
    for (int k = 0; k < DOUT; ++k) acc += ss[k] * V[k * DOUT + col];
    out[(size_t)r * DOUT + col] = fmaxf(acc, 0.f);
}

static inline size_t align256(size_t v) { return (v + 255) & ~(size_t)255; }

extern "C" void kernel_launch(void* const* d_in, const int* in_sizes, int n_in,
                              void* d_out, int out_size, void* d_ws, size_t ws_size,
                              hipStream_t stream) {
    const float* x    = (const float*)d_in[0];
    const float* h    = (const float*)d_in[1];
    const int*   rows = (const int*)d_in[2];
    const int*   cols = (const int*)d_in[3];
    const float* vals = (const float*)d_in[4];
    const float* W    = (const float*)d_in[5];
    const float* V    = (const float*)d_in[6];
    // d_in[7] (alpha): softmax over a size-1 axis == 1 -> dead.

    int nE = in_sizes[2];              // D*E = 6.4M
    int N  = in_sizes[1] / DOUT;       // 50000
    int nb = (N + BROWS - 1) / BROWS;  // 782 buckets
    float* out = (float*)d_out;
    float regInv = (float)NREG / (float)N;

    // ws: hV[N*128 bf16] | WT[128x256 bf16] | VT[128x128 bf16] |
    //     gcnt | bptr | gcur | ecv4[nE u32] | erow[nE u8]
    size_t o_hV   = 0;
    size_t o_WT   = o_hV   + align256((size_t)N * DOUT * 2);
    size_t o_VT   = o_WT   + align256((size_t)128 * 256 * 2);
    size_t o_gcnt = o_VT   + align256((size_t)128 * 128 * 2);
    size_t o_bptr = o_gcnt + align256((size_t)nb * 4);
    size_t o_gcur = o_bptr + align256((size_t)(nb + 1) * 4);
    size_t o_ecv4 = o_gcur + align256((size_t)nb * 4);
    size_t o_erow = o_ecv4 + align256((size_t)nE * 4);
    size_t need   = o_erow + (size_t)nE;

    if (ws_size >= need && N < 65536 && nb <= MAXNB) {
        char* p = (char*)d_ws;
        unsigned short* hV = (unsigned short*)(p + o_hV);
        unsigned short* WT = (unsigned short*)(p + o_WT);
        unsigned short* VT = (unsigned short*)(p + o_VT);
        int*      gcnt = (int*)(p + o_gcnt);
        int*      bptr = (int*)(p + o_bptr);
        int*      gcur = (int*)(p + o_gcur);
        unsigned* ecv4 = (unsigned*)(p + o_ecv4);
        unsigned char* erow = (unsigned char*)(p + o_erow);

        conv_wv<<<128, 256, 0, stream>>>(W, V, WT, VT);
        hv_gemm<<<(N + 63) / 64, 256, 0, stream>>>(h, (const unsigned*)VT, hV, N);
        hipMemsetAsync(gcnt, 0, (size_t)nb * 4, stream);
        bucket_hist<<<1024, 256, 0, stream>>>(rows, gcnt, nE, nb);
        scan_buckets<<<1, 1024, 0, stream>>>(gcnt, bptr, gcur, nb);
        bin_edges<<<(nE + BIN_CHUNK - 1) / BIN_CHUNK, 1024, 0, stream>>>(
            rows, cols, vals, gcur, ecv4, erow, nE, nb, regInv);
        spmm_epi<<<nb, 512, 0, stream>>>(bptr, ecv4, erow, (const unsigned*)hV,
                                         x, (const unsigned*)WT, out, N);
    } else {
        hipMemsetAsync(out, 0, (size_t)N * DOUT * 4, stream);
        spmm_atomic<<<(nE + 3) / 4, 256, 0, stream>>>(rows, cols, vals, h, out, nE);
        fused_out_full<<<N, 128, 0, stream>>>(x, W, V, out, N);
    }
}